// Round 3
// baseline (1130.108 us; speedup 1.0000x reference)
//
#include <hip/hip_runtime.h>
#include <stdint.h>

#define N_NODES 100000
#define N_EDGES 3200000
#define N_GRAPHS 512
#define DIM 128
#define M_PAD 100096          // N_NODES padded to multiple of 64
#define NGB (M_PAD / 256)     // 391 gemm blocks (256 rows each)
#define NBUCK 391             // buckets of 256 dst nodes: 391*256 = 100096 >= 100000
#define CAP 9216              // per-bucket region capacity; mean ~8184, sigma ~90
#define TILE 4096             // edges per block in k_bucket
#define NTILE 782             // ceil(3.2M / 4096)
#define XMM_NB 392            // stage-1 blocks for x min/max
#define NTEAM 4               // dim slices (32 dims each); slice s resident on XCDs {s, s+4}
#define ZROW N_NODES          // guaranteed-zero row (per slice) for masked tail edges

typedef __bf16 bf16x8 __attribute__((ext_vector_type(8)));
typedef float f32x4 __attribute__((ext_vector_type(4)));

__device__ __forceinline__ unsigned short f2bf(float f) {
  unsigned u = __float_as_uint(f);
  u = u + 0x7FFFu + ((u >> 16) & 1u);      // round-to-nearest-even
  return (unsigned short)(u >> 16);
}
__device__ __forceinline__ float bflo(unsigned v) { return __uint_as_float(v << 16); }
__device__ __forceinline__ float bfhi(unsigned v) { return __uint_as_float(v & 0xFFFF0000u); }
__device__ __forceinline__ float bfs(unsigned short v) { return __uint_as_float(((unsigned)v) << 16); }
__device__ __forceinline__ unsigned packbf(float a, float b) {
  return (unsigned)f2bf(a) | ((unsigned)f2bf(b) << 16);
}

// ---------------- CSR build: tiled-reservation counting sort ----------------
__global__ void k_zero32(int* __restrict__ p, int n) {
  int i = blockIdx.x * 256 + threadIdx.x;
  if (i < n) p[i] = 0;
}

__global__ __launch_bounds__(256) void k_bucket(const int* __restrict__ ei,
                                                int* __restrict__ cnt,
                                                unsigned* __restrict__ rec) {
  __shared__ int hist[NBUCK];
  __shared__ int curs[NBUCK];
  int t = threadIdx.x;
  int base_e = blockIdx.x * TILE;
  int es[16], ed[16];
#pragma unroll
  for (int k = 0; k < 16; ++k) {
    int e = base_e + k * 256 + t;
    if (e < N_EDGES) { es[k] = ei[e]; ed[k] = ei[N_EDGES + e]; }
    else ed[k] = -1;
  }
  for (int i = t; i < NBUCK; i += 256) hist[i] = 0;
  __syncthreads();
#pragma unroll
  for (int k = 0; k < 16; ++k)
    if (ed[k] >= 0) atomicAdd(&hist[ed[k] >> 8], 1);
  __syncthreads();
  for (int i = t; i < NBUCK; i += 256) {
    int h = hist[i];
    int g = h ? atomicAdd(&cnt[i], h) : 0;
    curs[i] = i * CAP + g;
  }
  __syncthreads();
#pragma unroll
  for (int k = 0; k < 16; ++k) {
    if (ed[k] >= 0) {
      int b = ed[k] >> 8;
      int pos = atomicAdd(&curs[b], 1);
      rec[pos] = ((unsigned)es[k] << 8) | (unsigned)(ed[k] & 255);
    }
  }
}

__global__ __launch_bounds__(512) void k_bscan(const int* __restrict__ cnt,
                                               int* __restrict__ bbase,
                                               int* __restrict__ row_ptr) {
  __shared__ int sc[512];
  int t = threadIdx.x;
  int tot = (t < NBUCK) ? min(cnt[t], CAP) : 0;
  sc[t] = tot; __syncthreads();
  for (int off = 1; off < 512; off <<= 1) {
    int x = (t >= off) ? sc[t - off] : 0;
    __syncthreads();
    sc[t] += x;
    __syncthreads();
  }
  if (t < NBUCK) bbase[t] = sc[t] - tot;                 // exclusive
  if (t == NBUCK - 1) {
    bbase[NBUCK] = sc[t];
    row_ptr[N_NODES] = sc[t];                            // == N_EDGES
  }
}

__global__ __launch_bounds__(256) void k_build(const unsigned* __restrict__ rec,
                                               const int* __restrict__ cnt,
                                               const int* __restrict__ bbase,
                                               int* __restrict__ row_ptr,
                                               int* __restrict__ col) {
  __shared__ int hist[256];
  __shared__ int sc[256];
  __shared__ int curs[256];
  int b = blockIdx.x, t = threadIdx.x;
  int n = min(cnt[b], CAP);
  const unsigned* p = rec + (size_t)b * CAP;
  hist[t] = 0; __syncthreads();
  for (int i = t; i < n; i += 256) atomicAdd(&hist[p[i] & 255u], 1);
  __syncthreads();
  int v = hist[t];
  sc[t] = v; __syncthreads();
  for (int off = 1; off < 256; off <<= 1) {
    int x = (t >= off) ? sc[t - off] : 0;
    __syncthreads();
    sc[t] += x;
    __syncthreads();
  }
  int excl = bbase[b] + sc[t] - v;
  int node = (b << 8) + t;
  if (node < N_NODES) row_ptr[node] = excl;
  curs[t] = excl;
  __syncthreads();
  for (int i = t; i < n; i += 256) {
    unsigned w = p[i];
    int pos = atomicAdd(&curs[w & 255u], 1);
    col[pos] = (int)(w >> 8);
  }
}

// ---------------- x per-column range: two-stage reduction ----------------
__global__ __launch_bounds__(256) void k_xmm1(const float* __restrict__ x,
                                              float* __restrict__ pmax,
                                              float* __restrict__ pmin) {
  __shared__ float smx[8][32][4];
  __shared__ float smn[8][32][4];
  int t = threadIdx.x;
  int c4 = t & 31;          // float4 column group
  int ro = t >> 5;          // 0..7
  float mx0 = 0.f, mx1 = 0.f, mx2 = 0.f, mx3 = 0.f;
  float mn0 = 0.f, mn1 = 0.f, mn2 = 0.f, mn3 = 0.f;
  for (int row = blockIdx.x * 8 + ro; row < N_NODES; row += XMM_NB * 8) {
    float4 v = ((const float4*)x)[(size_t)row * 32 + c4];
    mx0 = fmaxf(mx0, v.x); mn0 = fmaxf(mn0, -v.x);
    mx1 = fmaxf(mx1, v.y); mn1 = fmaxf(mn1, -v.y);
    mx2 = fmaxf(mx2, v.z); mn2 = fmaxf(mn2, -v.z);
    mx3 = fmaxf(mx3, v.w); mn3 = fmaxf(mn3, -v.w);
  }
  smx[ro][c4][0] = mx0; smx[ro][c4][1] = mx1; smx[ro][c4][2] = mx2; smx[ro][c4][3] = mx3;
  smn[ro][c4][0] = mn0; smn[ro][c4][1] = mn1; smn[ro][c4][2] = mn2; smn[ro][c4][3] = mn3;
  __syncthreads();
  for (int off = 4; off > 0; off >>= 1) {
    if (ro < off) {
#pragma unroll
      for (int k = 0; k < 4; ++k) {
        smx[ro][c4][k] = fmaxf(smx[ro][c4][k], smx[ro + off][c4][k]);
        smn[ro][c4][k] = fmaxf(smn[ro][c4][k], smn[ro + off][c4][k]);
      }
    }
    __syncthreads();
  }
  if (ro == 0) {
#pragma unroll
    for (int k = 0; k < 4; ++k) {
      pmax[blockIdx.x * 128 + c4 * 4 + k] = smx[0][c4][k];
      pmin[blockIdx.x * 128 + c4 * 4 + k] = smn[0][c4][k];
    }
  }
}

__global__ __launch_bounds__(64) void k_xmm2(const float* __restrict__ pmax,
                                             const float* __restrict__ pmin,
                                             float* __restrict__ xmx,
                                             float* __restrict__ xminf) {
  int c = blockIdx.x & 127;
  int isMin = blockIdx.x >> 7;
  const float* src = isMin ? pmin : pmax;
  int l = threadIdx.x;
  float m = 0.f;
  for (int p2 = l; p2 < XMM_NB; p2 += 64) m = fmaxf(m, src[p2 * 128 + c]);
#pragma unroll
  for (int off = 32; off > 0; off >>= 1) m = fmaxf(m, __shfl_down(m, off));
  if (l == 0) {
    if (isMin) xminf[c] = -m;
    else xmx[c] = m;
  }
}

// hmax partial reduce: block c reduces pmaxb[:, c] -> hmax[c]
__global__ __launch_bounds__(64) void k_hred(const float* __restrict__ pmaxb,
                                             float* __restrict__ hmax) {
  int c = blockIdx.x;
  float m = 0.f;
  for (int b = threadIdx.x; b < NGB; b += 64) m = fmaxf(m, pmaxb[(size_t)b * 128 + c]);
#pragma unroll
  for (int off = 32; off > 0; off >>= 1) m = fmaxf(m, __shfl_down(m, off));
  if (threadIdx.x == 0) hmax[c] = m;
}

// ---------------- conversions / coefficients ----------------
// Quantized tables are SLICE-MAJOR: u16 index = (lane>>4)*(M_PAD*16) + node*16 + (lane&15)
// i.e. [slice][node][16 u16 = 32 dims].  Pad nodes (>= N_NODES) are zero in every slice.
__global__ void k_convx(const float* __restrict__ x, const float* __restrict__ qmin,
                        const float* __restrict__ qmax, unsigned short* __restrict__ xq) {
  int i = blockIdx.x * 256 + threadIdx.x;
  if (i >= M_PAD * 64) return;
  int lane = i & 63;
  int node = i >> 6;
  unsigned short o = 0;
  if (node < N_NODES) {
    float mn0 = qmin[2 * lane], mn1 = qmin[2 * lane + 1];
    float r0 = qmax[2 * lane] - mn0, r1 = qmax[2 * lane + 1] - mn1;
    float is0 = r0 > 1e-20f ? 255.f / r0 : 0.f;
    float is1 = r1 > 1e-20f ? 255.f / r1 : 0.f;
    float2 f = ((const float2*)x)[i];
    int q0 = (int)rintf((f.x - mn0) * is0); q0 = min(max(q0, 0), 255);
    int q1 = (int)rintf((f.y - mn1) * is1); q1 = min(max(q1, 0), 255);
    o = (unsigned short)(q0 | (q1 << 8));
  }
  xq[(size_t)(lane >> 4) * (M_PAD * 16) + (size_t)node * 16 + (lane & 15)] = o;
}

// h (bf16x2-packed) -> u8 (min = 0), sliced output layout
__global__ void k_quant(const unsigned* __restrict__ hbf, const float* __restrict__ qmax,
                        unsigned short* __restrict__ hq) {
  int i = blockIdx.x * 256 + threadIdx.x;
  if (i >= M_PAD * 64) return;
  int lane = i & 63;
  int node = i >> 6;
  size_t oidx = (size_t)(lane >> 4) * (M_PAD * 16) + (size_t)node * 16 + (lane & 15);
  if (node >= N_NODES) { hq[oidx] = 0; return; }
  float mx0 = qmax[2 * lane], mx1 = qmax[2 * lane + 1];
  float is0 = mx0 > 1e-20f ? 255.f / mx0 : 0.f;
  float is1 = mx1 > 1e-20f ? 255.f / mx1 : 0.f;
  unsigned v = hbf[i];
  int q0 = (int)rintf(bflo(v) * is0); q0 = min(max(q0, 0), 255);
  int q1 = (int)rintf(bfhi(v) * is1); q1 = min(max(q1, 0), 255);
  hq[oidx] = (unsigned short)(q0 | (q1 << 8));
}

__global__ void k_convw(const float* __restrict__ W1, const float* __restrict__ W2,
                        unsigned short* __restrict__ Wt1, unsigned short* __restrict__ Wt2) {
  int i = blockIdx.x * 256 + threadIdx.x;
  if (i >= 3 * DIM * DIM) return;
  int l = i >> 14, rem = i & 16383, k = rem >> 7, n = rem & 127;
  int o = (l << 14) + (n << 7) + k;          // transposed: Wt[l][n][k]
  Wt1[o] = f2bf(W1[i]);
  Wt2[o] = f2bf(W2[i]);
}

__global__ void k_coef(const float* __restrict__ b1, const float* __restrict__ gamma,
                       const float* __restrict__ beta, const float* __restrict__ rmean,
                       const float* __restrict__ rvar, const float* __restrict__ b2,
                       float* __restrict__ sA1, float* __restrict__ sB1,
                       float* __restrict__ sA2, float* __restrict__ sB2) {
  int i = blockIdx.x * 128 + threadIdx.x;
  if (i >= 3 * DIM) return;
  float sa = gamma[i] * rsqrtf(rvar[i] + 1e-5f);
  sA1[i] = sa;
  sB1[i] = fmaf(sa, b1[i] - rmean[i], beta[i]);  // sa*(b1-rmean)+beta
  sA2[i] = 1.0f;
  sB2[i] = b2[i];
}

// ---------------- aggregation v6: dim-sliced, XCD-resident table ----------------
// 4 teams x 32 dims.  block bid: team = bid&3 (round-robin bid%8 -> XCD puts slice s
// on XCDs {s, s+4} only; slice table = 3.2 MB < 4 MiB per-XCD L2 -> gathers become
// L2 hits, FETCH_SIZE collapses to compulsory fills + col streaming).
// One lane = one node: accumulates all its edges' 32-dim u8 slices into u16x2
// registers (max deg ~70 -> sums <= 255*71 < 65535), then dequants + writes 64 B.
// No cross-lane ops at all.  Bit-identical numerics (integer adds commute).
#define ACCP(v, E, O) { E += (v) & 0x00FF00FFu; O += ((v) >> 8) & 0x00FF00FFu; }

__device__ __forceinline__ uint2 dq2(unsigned ev, unsigned od, float4 qn, float4 qx, float cntf) {
  const float k255 = 1.0f / 255.0f;
  float A0 = fmaf(qn.x, cntf, (qx.x - qn.x) * k255 * (float)(ev & 0xFFFFu));
  float A1 = fmaf(qn.y, cntf, (qx.y - qn.y) * k255 * (float)(od & 0xFFFFu));
  float A2 = fmaf(qn.z, cntf, (qx.z - qn.z) * k255 * (float)(ev >> 16));
  float A3 = fmaf(qn.w, cntf, (qx.w - qn.w) * k255 * (float)(od >> 16));
  return make_uint2(packbf(A0, A1), packbf(A2, A3));
}

__global__ __launch_bounds__(256) void k_aggr(const unsigned short* __restrict__ hq,
                                              const int* __restrict__ row_ptr,
                                              const int* __restrict__ col,
                                              const float* __restrict__ qmin,
                                              const float* __restrict__ qmax,
                                              unsigned* __restrict__ tmp) {
  int team = blockIdx.x & (NTEAM - 1);     // dim slice [32*team, 32*team+32)
  int nr = blockIdx.x >> 2;                // node range
  int node = (nr << 8) + threadIdx.x;      // one node per lane
  const uint4* hs = (const uint4*)((const unsigned short*)hq + (size_t)team * (M_PAD * 16));
  bool valid = node < N_NODES;
  int s = valid ? row_ptr[node] : 0;
  int e = valid ? row_ptr[node + 1] : 0;
  int deg = e - s;
  // wave-uniform trip count
  int dmax = deg;
#pragma unroll
  for (int off = 32; off > 0; off >>= 1) dmax = max(dmax, __shfl_xor(dmax, off));

  unsigned ev[8], od[8];
#pragma unroll
  for (int g = 0; g < 8; ++g) { ev[g] = 0u; od[g] = 0u; }

  for (int e0 = 0; e0 < dmax; e0 += 4) {
    int c[4];
#pragma unroll
    for (int u = 0; u < 4; ++u)
      c[u] = (e0 + u < deg) ? col[s + e0 + u] : ZROW;   // ZROW = all-zero row in this slice
    uint4 ga[4], gb[4];
#pragma unroll
    for (int u = 0; u < 4; ++u) {
      ga[u] = hs[(size_t)c[u] * 2];
      gb[u] = hs[(size_t)c[u] * 2 + 1];
    }
#pragma unroll
    for (int u = 0; u < 4; ++u) {
      ACCP(ga[u].x, ev[0], od[0]); ACCP(ga[u].y, ev[1], od[1]);
      ACCP(ga[u].z, ev[2], od[2]); ACCP(ga[u].w, ev[3], od[3]);
      ACCP(gb[u].x, ev[4], od[4]); ACCP(gb[u].y, ev[5], od[5]);
      ACCP(gb[u].z, ev[6], od[6]); ACCP(gb[u].w, ev[7], od[7]);
    }
  }

  uint4* dst = (uint4*)(tmp + (size_t)node * 64 + team * 16);
  if (valid) {
    // self term (eps=0: x + sum_neighbors)
    uint4 sa = hs[(size_t)node * 2];
    uint4 sb = hs[(size_t)node * 2 + 1];
    ACCP(sa.x, ev[0], od[0]); ACCP(sa.y, ev[1], od[1]);
    ACCP(sa.z, ev[2], od[2]); ACCP(sa.w, ev[3], od[3]);
    ACCP(sb.x, ev[4], od[4]); ACCP(sb.y, ev[5], od[5]);
    ACCP(sb.z, ev[6], od[6]); ACCP(sb.w, ev[7], od[7]);
    float cntf = (float)(deg + 1);
    const float4* qnp = (const float4*)qmin + team * 8;  // uniform per block -> scalar loads
    const float4* qxp = (const float4*)qmax + team * 8;
    uint2 r[8];
#pragma unroll
    for (int g = 0; g < 8; ++g) r[g] = dq2(ev[g], od[g], qnp[g], qxp[g], cntf);
    dst[0] = make_uint4(r[0].x, r[0].y, r[1].x, r[1].y);
    dst[1] = make_uint4(r[2].x, r[2].y, r[3].x, r[3].y);
    dst[2] = make_uint4(r[4].x, r[4].y, r[5].x, r[5].y);
    dst[3] = make_uint4(r[6].x, r[6].y, r[7].x, r[7].y);
  } else {
    uint4 z = make_uint4(0u, 0u, 0u, 0u);
    dst[0] = z; dst[1] = z; dst[2] = z; dst[3] = z;
  }
}

// ---------------- fused layer: GEMM1 -> GEMM2 -> pooling (B in regs, z/h in LDS) ----------------
__global__ __launch_bounds__(256, 2) void k_gemm12(const unsigned short* __restrict__ A,
                                                   const unsigned short* __restrict__ Wt1,
                                                   const float* __restrict__ sA1,
                                                   const float* __restrict__ sB1,
                                                   const unsigned short* __restrict__ Wt2,
                                                   const float* __restrict__ sA2,
                                                   const float* __restrict__ sB2,
                                                   const int* __restrict__ batch,
                                                   unsigned short* __restrict__ out,
                                                   float* __restrict__ pooled8, int layer,
                                                   float* __restrict__ pmaxb, int do_max) {
  __shared__ unsigned short zt[4][64][136];   // z then h, wave-private rows
  __shared__ float colred[128];
  __shared__ int sgid[256];
  int w = threadIdx.x >> 6, lane = threadIdx.x & 63;
  int q = lane >> 4, n16 = lane & 15;
  int rbase = (blockIdx.x << 8) + (w << 6);
  if (do_max && threadIdx.x < 128) colred[threadIdx.x] = 0.f;
  {
    int rr = (blockIdx.x << 8) + threadIdx.x;
    sgid[threadIdx.x] = (rr < N_NODES) ? batch[rr] : -1;
  }

  // ---- phase 1: B1 in registers, z -> LDS ----
  {
    bf16x8 Bf[4][8];
#pragma unroll
    for (int ks = 0; ks < 4; ++ks)
#pragma unroll
      for (int c = 0; c < 8; ++c)
        Bf[ks][c] = *(const bf16x8*)(Wt1 + (size_t)((c << 4) + n16) * DIM + ks * 32 + q * 8);
#pragma unroll
    for (int t = 0; t < 4; ++t) {
      int r0 = rbase + (t << 4);
      f32x4 acc[8] = {};
#pragma unroll
      for (int ks = 0; ks < 4; ++ks) {
        bf16x8 a = *(const bf16x8*)(A + (size_t)(r0 + n16) * DIM + ks * 32 + q * 8);
#pragma unroll
        for (int c = 0; c < 8; ++c)
          acc[c] = __builtin_amdgcn_mfma_f32_16x16x32_bf16(a, Bf[ks][c], acc[c], 0, 0, 0);
      }
#pragma unroll
      for (int c = 0; c < 8; ++c) {
        int colc = (c << 4) + n16;
        float s = sA1[colc], tt = sB1[colc];
#pragma unroll
        for (int r = 0; r < 4; ++r) {
          float v = fmaxf(fmaf(s, acc[c][r], tt), 0.0f);
          zt[w][(t << 4) + (q << 2) + r][colc] = f2bf(v);
        }
      }
    }
  }

  // ---- phase 2: B2 in registers, A from LDS; h -> global + LDS ----
  float mcol[8];
#pragma unroll
  for (int c = 0; c < 8; ++c) mcol[c] = 0.f;
  {
    bf16x8 Bf[4][8];
#pragma unroll
    for (int ks = 0; ks < 4; ++ks)
#pragma unroll
      for (int c = 0; c < 8; ++c)
        Bf[ks][c] = *(const bf16x8*)(Wt2 + (size_t)((c << 4) + n16) * DIM + ks * 32 + q * 8);
#pragma unroll
    for (int t = 0; t < 4; ++t) {
      int r0 = rbase + (t << 4);
      f32x4 acc[8] = {};
#pragma unroll
      for (int ks = 0; ks < 4; ++ks) {
        bf16x8 a = *(const bf16x8*)(&zt[w][(t << 4) + n16][ks * 32 + q * 8]);
#pragma unroll
        for (int c = 0; c < 8; ++c)
          acc[c] = __builtin_amdgcn_mfma_f32_16x16x32_bf16(a, Bf[ks][c], acc[c], 0, 0, 0);
      }
      __builtin_amdgcn_s_waitcnt(0);   // all LDS reads of tile t done before overwrite (wave-level)
#pragma unroll
      for (int c = 0; c < 8; ++c) {
        int colc = (c << 4) + n16;
        float s = sA2[colc], tt = sB2[colc];
#pragma unroll
        for (int r = 0; r < 4; ++r) {
          float v = fmaxf(fmaf(s, acc[c][r], tt), 0.0f);
          mcol[c] = fmaxf(mcol[c], v);
          unsigned short hv = f2bf(v);
          out[(size_t)(r0 + (q << 2) + r) * DIM + colc] = hv;
          zt[w][(t << 4) + (q << 2) + r][colc] = hv;
        }
      }
    }
  }
  __syncthreads();   // h tiles + sgid visible to all

  // ---- pooling: segment-sum sorted rows, one atomic per (segment, col) ----
  {
    const unsigned short* ztf = &zt[0][0][0];
    int colp = threadIdx.x & 127, grp = threadIdx.x >> 7;
    int cp = blockIdx.x & 7;
    float pacc = 0.f;
    int gcur = sgid[grp << 7];
    for (int r = 0; r < 128; ++r) {
      int row = (grp << 7) + r;
      int g = sgid[row];
      if (g != gcur) {
        if (gcur >= 0)
          atomicAdd(&pooled8[((size_t)cp * N_GRAPHS + gcur) * 384 + layer * DIM + colp], pacc);
        pacc = 0.f; gcur = g;
      }
      if (g >= 0) pacc += bfs(ztf[row * 136 + colp]);
    }
    if (gcur >= 0)
      atomicAdd(&pooled8[((size_t)cp * N_GRAPHS + gcur) * 384 + layer * DIM + colp], pacc);
  }

  if (do_max) {
#pragma unroll
    for (int c = 0; c < 8; ++c)
      atomicMax((int*)&colred[(c << 4) + n16], __float_as_int(mcol[c]));
    __syncthreads();
    if (threadIdx.x < 128)
      pmaxb[(size_t)blockIdx.x * 128 + threadIdx.x] = colred[threadIdx.x];
  }
}

// ---------------- head: 8 graphs per block, sums the 8 pooled copies ----------------
__global__ __launch_bounds__(384) void k_head(const float* __restrict__ pooled8,
                                              const float* __restrict__ Wfin,
                                              const float* __restrict__ bfin,
                                              const float* __restrict__ Wout,
                                              const float* __restrict__ bout,
                                              float* __restrict__ out) {
  __shared__ float p[8][384];
  __shared__ float hf[8][392];
  __shared__ float lg[8][10];
  __shared__ float lse[8];
  int t = threadIdx.x, g0 = blockIdx.x << 3;
  for (int i = t; i < 8 * 384; i += 384) {
    int gl = i / 384, k = i % 384;
    float s = 0.f;
#pragma unroll
    for (int cp = 0; cp < 8; ++cp)
      s += pooled8[((size_t)cp * N_GRAPHS + g0 + gl) * 384 + k];
    p[gl][k] = s;
  }
  __syncthreads();
  float bb = bfin[t];
  float acc[8];
#pragma unroll
  for (int g = 0; g < 8; ++g) acc[g] = bb;
  for (int k = 0; k < 384; ++k) {
    float wv = Wfin[k * 384 + t];
#pragma unroll
    for (int g = 0; g < 8; ++g) acc[g] = fmaf(p[g][k], wv, acc[g]);
  }
#pragma unroll
  for (int g = 0; g < 8; ++g) hf[g][t] = fmaxf(acc[g], 0.f);
  __syncthreads();
  if (t < 80) {
    int g = t / 10, c = t % 10;
    float a = bout[c];
    for (int k = 0; k < 384; ++k) a = fmaf(hf[g][k], Wout[k * 10 + c], a);
    lg[g][c] = a;
  }
  __syncthreads();
  if (t < 8) {
    float m = lg[t][0];
#pragma unroll
    for (int i = 1; i < 10; ++i) m = fmaxf(m, lg[t][i]);
    float ss = 0.f;
#pragma unroll
    for (int i = 0; i < 10; ++i) ss += __expf(lg[t][i] - m);
    lse[t] = m + __logf(ss);
  }
  __syncthreads();
  if (t < 80) {
    int g = t / 10, c = t % 10;
    out[(size_t)(g0 + g) * 10 + c] = lg[g][c];
    out[(size_t)N_GRAPHS * 10 + (size_t)(g0 + g) * 10 + c] = lg[g][c] - lse[g];
  }
}

extern "C" void kernel_launch(void* const* d_in, const int* in_sizes, int n_in,
                              void* d_out, int out_size, void* d_ws, size_t ws_size,
                              hipStream_t stream) {
  const float* x     = (const float*)d_in[0];
  const int*   ei    = (const int*)d_in[1];    // [2, N_EDGES]: src then dst
  const int*   batch = (const int*)d_in[2];
  const float* W1    = (const float*)d_in[4];
  const float* b1    = (const float*)d_in[5];
  const float* gamma = (const float*)d_in[6];
  const float* beta  = (const float*)d_in[7];
  const float* rmean = (const float*)d_in[8];
  const float* rvar  = (const float*)d_in[9];
  const float* W2    = (const float*)d_in[10];
  const float* b2    = (const float*)d_in[11];
  const float* Wfin  = (const float*)d_in[12];
  const float* bfin  = (const float*)d_in[13];
  const float* Wout  = (const float*)d_in[14];
  const float* bout  = (const float*)d_in[15];
  float* out = (float*)d_out;

  char* p = (char*)d_ws;
  auto alloc = [&](size_t bytes) { char* r = p; p += (bytes + 255) & ~255ull; return r; };
  int* cnt      = (int*)alloc(NBUCK * 4);
  unsigned* rec = (unsigned*)alloc((size_t)NBUCK * CAP * 4);
  int* bbase    = (int*)alloc((NBUCK + 1) * 4);
  int* row_ptr  = (int*)alloc((N_NODES + 1) * 4);
  int* colb     = (int*)alloc(((size_t)N_EDGES + 256) * 4);   // +256 pad: masked overreads in k_aggr
  unsigned short* xq  = (unsigned short*)alloc((size_t)M_PAD * 64 * 2);
  unsigned short* hqb = (unsigned short*)alloc((size_t)M_PAD * 64 * 2);
  unsigned* hbf  = (unsigned*)alloc((size_t)M_PAD * 64 * 4);
  unsigned* tmpb = (unsigned*)alloc((size_t)M_PAD * 64 * 4);
  unsigned short* Wt1 = (unsigned short*)alloc(3 * DIM * DIM * 2);
  unsigned short* Wt2 = (unsigned short*)alloc(3 * DIM * DIM * 2);
  float* pmax   = (float*)alloc((size_t)XMM_NB * 128 * 4);
  float* pmin   = (float*)alloc((size_t)XMM_NB * 128 * 4);
  float* pmaxb  = (float*)alloc((size_t)NGB * 128 * 4);
  float* sA1    = (float*)alloc(384 * 4);
  float* sB1    = (float*)alloc(384 * 4);
  float* sA2    = (float*)alloc(384 * 4);
  float* sB2    = (float*)alloc(384 * 4);
  float* qbuf   = (float*)alloc(1024 * 4);
  float* xmx    = qbuf + 128;    // max(v,0)
  float* xminf  = qbuf + 256;    // min(v,0)
  float* hmax0  = qbuf + 384;
  float* hmax1  = qbuf + 512;
  float* zeros  = qbuf + 640;    // 128 zeros (qmin for relu'd h)
  float* pooled8 = (float*)alloc((size_t)8 * N_GRAPHS * 384 * 4);

  k_zero32<<<(NBUCK + 255) / 256, 256, 0, stream>>>(cnt, NBUCK);
  k_zero32<<<4, 256, 0, stream>>>((int*)qbuf, 1024);
  k_zero32<<<(8 * N_GRAPHS * 384 + 255) / 256, 256, 0, stream>>>((int*)pooled8, 8 * N_GRAPHS * 384);

  // CSR build via tiled-reservation counting sort (edges constant across layers)
  k_bucket<<<NTILE, 256, 0, stream>>>(ei, cnt, rec);
  k_bscan<<<1, 512, 0, stream>>>(cnt, bbase, row_ptr);
  k_build<<<NBUCK, 256, 0, stream>>>(rec, cnt, bbase, row_ptr, colb);

  k_xmm1<<<XMM_NB, 256, 0, stream>>>(x, pmax, pmin);
  k_xmm2<<<256, 64, 0, stream>>>(pmax, pmin, xmx, xminf);
  k_convx<<<(M_PAD * 64 + 255) / 256, 256, 0, stream>>>(x, xminf, xmx, xq);
  k_convw<<<(3 * DIM * DIM + 255) / 256, 256, 0, stream>>>(W1, W2, Wt1, Wt2);
  k_coef<<<3, 128, 0, stream>>>(b1, gamma, beta, rmean, rvar, b2, sA1, sB1, sA2, sB2);

  // layer 0
  k_aggr<<<NGB * NTEAM, 256, 0, stream>>>(xq, row_ptr, colb, xminf, xmx, tmpb);
  k_gemm12<<<NGB, 256, 0, stream>>>((const unsigned short*)tmpb, Wt1, sA1, sB1,
                                    Wt2, sA2, sB2, batch, (unsigned short*)hbf,
                                    pooled8, 0, pmaxb, 1);
  k_hred<<<128, 64, 0, stream>>>(pmaxb, hmax0);
  k_quant<<<(M_PAD * 64 + 255) / 256, 256, 0, stream>>>(hbf, hmax0, hqb);
  // layer 1
  k_aggr<<<NGB * NTEAM, 256, 0, stream>>>(hqb, row_ptr, colb, zeros, hmax0, tmpb);
  k_gemm12<<<NGB, 256, 0, stream>>>((const unsigned short*)tmpb, Wt1 + DIM * DIM,
                                    sA1 + DIM, sB1 + DIM, Wt2 + DIM * DIM,
                                    sA2 + DIM, sB2 + DIM, batch, (unsigned short*)hbf,
                                    pooled8, 1, pmaxb, 1);
  k_hred<<<128, 64, 0, stream>>>(pmaxb, hmax1);
  k_quant<<<(M_PAD * 64 + 255) / 256, 256, 0, stream>>>(hbf, hmax1, hqb);
  // layer 2 (h never gathered again: no max/quant)
  k_aggr<<<NGB * NTEAM, 256, 0, stream>>>(hqb, row_ptr, colb, zeros, hmax1, tmpb);
  k_gemm12<<<NGB, 256, 0, stream>>>((const unsigned short*)tmpb, Wt1 + 2 * DIM * DIM,
                                    sA1 + 2 * DIM, sB1 + 2 * DIM, Wt2 + 2 * DIM * DIM,
                                    sA2 + 2 * DIM, sB2 + 2 * DIM, batch, (unsigned short*)hbf,
                                    pooled8, 2, pmaxb, 0);

  k_head<<<N_GRAPHS / 8, 384, 0, stream>>>(pooled8, Wfin, bfin, Wout, bout, out);
}

// Round 4
// 602.624 us; speedup vs baseline: 1.8753x; 1.8753x over previous
//
#include <hip/hip_runtime.h>
#include <stdint.h>

#define N_NODES 100000
#define N_EDGES 3200000
#define N_GRAPHS 512
#define DIM 128
#define M_PAD 100096          // N_NODES padded to multiple of 64
#define NGB (M_PAD / 256)     // 391 gemm blocks (256 rows each)
#define NBUCK 391             // buckets of 256 dst nodes: 391*256 = 100096 >= 100000
#define CAP 9216              // per-bucket region capacity; mean ~8184, sigma ~90
#define TILE 4096             // edges per block in k_bucket
#define NTILE 782             // ceil(3.2M / 4096)
#define XMM_NB 392            // stage-1 blocks for x min/max
#define NPOOL (8 * N_GRAPHS * 384)

typedef __bf16 bf16x8 __attribute__((ext_vector_type(8)));
typedef float f32x4 __attribute__((ext_vector_type(4)));

__device__ __forceinline__ unsigned short f2bf(float f) {
  unsigned u = __float_as_uint(f);
  u = u + 0x7FFFu + ((u >> 16) & 1u);      // round-to-nearest-even
  return (unsigned short)(u >> 16);
}
__device__ __forceinline__ float bflo(unsigned v) { return __uint_as_float(v << 16); }
__device__ __forceinline__ float bfhi(unsigned v) { return __uint_as_float(v & 0xFFFF0000u); }
__device__ __forceinline__ float bfs(unsigned short v) { return __uint_as_float(((unsigned)v) << 16); }
__device__ __forceinline__ unsigned packbf(float a, float b) {
  return (unsigned)f2bf(a) | ((unsigned)f2bf(b) << 16);
}

// ---------------- combined zeroing (one launch) ----------------
__global__ void k_zeroall(int* __restrict__ cnt, int* __restrict__ qbuf,
                          int* __restrict__ pooled) {
  int i = blockIdx.x * 256 + threadIdx.x;
  if (i < NBUCK) cnt[i] = 0;
  if (i < 1024) qbuf[i] = 0;
  if (i < NPOOL) pooled[i] = 0;
}

// ---------------- CSR build: tiled-reservation counting sort ----------------
__global__ __launch_bounds__(256) void k_bucket(const int* __restrict__ ei,
                                                int* __restrict__ cnt,
                                                unsigned* __restrict__ rec) {
  __shared__ int hist[NBUCK];
  __shared__ int curs[NBUCK];
  int t = threadIdx.x;
  int base_e = blockIdx.x * TILE;
  int es[16], ed[16];
#pragma unroll
  for (int k = 0; k < 16; ++k) {
    int e = base_e + k * 256 + t;
    if (e < N_EDGES) { es[k] = ei[e]; ed[k] = ei[N_EDGES + e]; }
    else ed[k] = -1;
  }
  for (int i = t; i < NBUCK; i += 256) hist[i] = 0;
  __syncthreads();
#pragma unroll
  for (int k = 0; k < 16; ++k)
    if (ed[k] >= 0) atomicAdd(&hist[ed[k] >> 8], 1);
  __syncthreads();
  for (int i = t; i < NBUCK; i += 256) {
    int h = hist[i];
    int g = h ? atomicAdd(&cnt[i], h) : 0;
    curs[i] = i * CAP + g;
  }
  __syncthreads();
#pragma unroll
  for (int k = 0; k < 16; ++k) {
    if (ed[k] >= 0) {
      int b = ed[k] >> 8;
      int pos = atomicAdd(&curs[b], 1);
      rec[pos] = ((unsigned)es[k] << 8) | (unsigned)(ed[k] & 255);
    }
  }
}

__global__ __launch_bounds__(512) void k_bscan(const int* __restrict__ cnt,
                                               int* __restrict__ bbase,
                                               int* __restrict__ row_ptr) {
  __shared__ int sc[512];
  int t = threadIdx.x;
  int tot = (t < NBUCK) ? min(cnt[t], CAP) : 0;
  sc[t] = tot; __syncthreads();
  for (int off = 1; off < 512; off <<= 1) {
    int x = (t >= off) ? sc[t - off] : 0;
    __syncthreads();
    sc[t] += x;
    __syncthreads();
  }
  if (t < NBUCK) bbase[t] = sc[t] - tot;                 // exclusive
  if (t == NBUCK - 1) {
    bbase[NBUCK] = sc[t];
    row_ptr[N_NODES] = sc[t];                            // == N_EDGES
  }
}

__global__ __launch_bounds__(256) void k_build(const unsigned* __restrict__ rec,
                                               const int* __restrict__ cnt,
                                               const int* __restrict__ bbase,
                                               int* __restrict__ row_ptr,
                                               int* __restrict__ col) {
  __shared__ int hist[256];
  __shared__ int sc[256];
  __shared__ int curs[256];
  int b = blockIdx.x, t = threadIdx.x;
  int n = min(cnt[b], CAP);
  const unsigned* p = rec + (size_t)b * CAP;
  hist[t] = 0; __syncthreads();
  for (int i = t; i < n; i += 256) atomicAdd(&hist[p[i] & 255u], 1);
  __syncthreads();
  int v = hist[t];
  sc[t] = v; __syncthreads();
  for (int off = 1; off < 256; off <<= 1) {
    int x = (t >= off) ? sc[t - off] : 0;
    __syncthreads();
    sc[t] += x;
    __syncthreads();
  }
  int excl = bbase[b] + sc[t] - v;
  int node = (b << 8) + t;
  if (node < N_NODES) row_ptr[node] = excl;
  curs[t] = excl;
  __syncthreads();
  for (int i = t; i < n; i += 256) {
    unsigned w = p[i];
    int pos = atomicAdd(&curs[w & 255u], 1);
    col[pos] = (int)(w >> 8);
  }
}

// ---------------- x per-column range: two-stage reduction ----------------
__global__ __launch_bounds__(256) void k_xmm1(const float* __restrict__ x,
                                              float* __restrict__ pmax,
                                              float* __restrict__ pmin) {
  __shared__ float smx[8][32][4];
  __shared__ float smn[8][32][4];
  int t = threadIdx.x;
  int c4 = t & 31;          // float4 column group
  int ro = t >> 5;          // 0..7
  float mx0 = 0.f, mx1 = 0.f, mx2 = 0.f, mx3 = 0.f;
  float mn0 = 0.f, mn1 = 0.f, mn2 = 0.f, mn3 = 0.f;
  for (int row = blockIdx.x * 8 + ro; row < N_NODES; row += XMM_NB * 8) {
    float4 v = ((const float4*)x)[(size_t)row * 32 + c4];
    mx0 = fmaxf(mx0, v.x); mn0 = fmaxf(mn0, -v.x);
    mx1 = fmaxf(mx1, v.y); mn1 = fmaxf(mn1, -v.y);
    mx2 = fmaxf(mx2, v.z); mn2 = fmaxf(mn2, -v.z);
    mx3 = fmaxf(mx3, v.w); mn3 = fmaxf(mn3, -v.w);
  }
  smx[ro][c4][0] = mx0; smx[ro][c4][1] = mx1; smx[ro][c4][2] = mx2; smx[ro][c4][3] = mx3;
  smn[ro][c4][0] = mn0; smn[ro][c4][1] = mn1; smn[ro][c4][2] = mn2; smn[ro][c4][3] = mn3;
  __syncthreads();
  for (int off = 4; off > 0; off >>= 1) {
    if (ro < off) {
#pragma unroll
      for (int k = 0; k < 4; ++k) {
        smx[ro][c4][k] = fmaxf(smx[ro][c4][k], smx[ro + off][c4][k]);
        smn[ro][c4][k] = fmaxf(smn[ro][c4][k], smn[ro + off][c4][k]);
      }
    }
    __syncthreads();
  }
  if (ro == 0) {
#pragma unroll
    for (int k = 0; k < 4; ++k) {
      pmax[blockIdx.x * 128 + c4 * 4 + k] = smx[0][c4][k];
      pmin[blockIdx.x * 128 + c4 * 4 + k] = smn[0][c4][k];
    }
  }
}

__global__ __launch_bounds__(64) void k_xmm2(const float* __restrict__ pmax,
                                             const float* __restrict__ pmin,
                                             float* __restrict__ xmx,
                                             float* __restrict__ xminf) {
  int c = blockIdx.x & 127;
  int isMin = blockIdx.x >> 7;
  const float* src = isMin ? pmin : pmax;
  int l = threadIdx.x;
  float m = 0.f;
  for (int p2 = l; p2 < XMM_NB; p2 += 64) m = fmaxf(m, src[p2 * 128 + c]);
#pragma unroll
  for (int off = 32; off > 0; off >>= 1) m = fmaxf(m, __shfl_down(m, off));
  if (l == 0) {
    if (isMin) xminf[c] = -m;
    else xmx[c] = m;
  }
}

// hmax partial reduce: block c reduces pmaxb[:, c] -> hmax[c]
__global__ __launch_bounds__(64) void k_hred(const float* __restrict__ pmaxb,
                                             float* __restrict__ hmax) {
  int c = blockIdx.x;
  float m = 0.f;
  for (int b = threadIdx.x; b < NGB; b += 64) m = fmaxf(m, pmaxb[(size_t)b * 128 + c]);
#pragma unroll
  for (int off = 32; off > 0; off >>= 1) m = fmaxf(m, __shfl_down(m, off));
  if (threadIdx.x == 0) hmax[c] = m;
}

// ---------------- conversions / coefficients ----------------
__global__ void k_convx(const float* __restrict__ x, const float* __restrict__ qmin,
                        const float* __restrict__ qmax, unsigned short* __restrict__ xq) {
  int i = blockIdx.x * 256 + threadIdx.x;
  if (i >= M_PAD * 64) return;
  int lane = i & 63;
  unsigned short o = 0;
  if ((i >> 6) < N_NODES) {
    float mn0 = qmin[2 * lane], mn1 = qmin[2 * lane + 1];
    float r0 = qmax[2 * lane] - mn0, r1 = qmax[2 * lane + 1] - mn1;
    float is0 = r0 > 1e-20f ? 255.f / r0 : 0.f;
    float is1 = r1 > 1e-20f ? 255.f / r1 : 0.f;
    float2 f = ((const float2*)x)[i];
    int q0 = (int)rintf((f.x - mn0) * is0); q0 = min(max(q0, 0), 255);
    int q1 = (int)rintf((f.y - mn1) * is1); q1 = min(max(q1, 0), 255);
    o = (unsigned short)(q0 | (q1 << 8));
  }
  xq[i] = o;
}

// h (bf16x2-packed) -> u8 (min = 0); padding rows forced to ZERO so k_aggr can
// use row N_NODES as a guaranteed-zero gather target for masked tail lanes.
__global__ void k_quant(const unsigned* __restrict__ hbf, const float* __restrict__ qmax,
                        unsigned short* __restrict__ hq) {
  int i = blockIdx.x * 256 + threadIdx.x;
  if (i >= M_PAD * 64) return;
  if ((i >> 6) >= N_NODES) { hq[i] = 0; return; }
  int lane = i & 63;
  float mx0 = qmax[2 * lane], mx1 = qmax[2 * lane + 1];
  float is0 = mx0 > 1e-20f ? 255.f / mx0 : 0.f;
  float is1 = mx1 > 1e-20f ? 255.f / mx1 : 0.f;
  unsigned v = hbf[i];
  int q0 = (int)rintf(bflo(v) * is0); q0 = min(max(q0, 0), 255);
  int q1 = (int)rintf(bfhi(v) * is1); q1 = min(max(q1, 0), 255);
  hq[i] = (unsigned short)(q0 | (q1 << 8));
}

__global__ void k_convw(const float* __restrict__ W1, const float* __restrict__ W2,
                        unsigned short* __restrict__ Wt1, unsigned short* __restrict__ Wt2) {
  int i = blockIdx.x * 256 + threadIdx.x;
  if (i >= 3 * DIM * DIM) return;
  int l = i >> 14, rem = i & 16383, k = rem >> 7, n = rem & 127;
  int o = (l << 14) + (n << 7) + k;          // transposed: Wt[l][n][k]
  Wt1[o] = f2bf(W1[i]);
  Wt2[o] = f2bf(W2[i]);
}

__global__ void k_coef(const float* __restrict__ b1, const float* __restrict__ gamma,
                       const float* __restrict__ beta, const float* __restrict__ rmean,
                       const float* __restrict__ rvar, const float* __restrict__ b2,
                       float* __restrict__ sA1, float* __restrict__ sB1,
                       float* __restrict__ sA2, float* __restrict__ sB2) {
  int i = blockIdx.x * 128 + threadIdx.x;
  if (i >= 3 * DIM) return;
  float sa = gamma[i] * rsqrtf(rvar[i] + 1e-5f);
  sA1[i] = sa;
  sB1[i] = fmaf(sa, b1[i] - rmean[i], beta[i]);  // sa*(b1-rmean)+beta
  sA2[i] = 1.0f;
  sB2[i] = b2[i];
}

// ---------------- aggregation v4 (u8): dwordx4 gathers, 8 edges per VMEM instr ----------------
// v4 is the measured best (57.5 us).  Law from v4/v5/v6: dur = FETCH_SIZE / ~2.8 TB/s;
// v4's FETCH (~158 MB) is within ~20% of the per-XCD compulsory floor for a random
// graph, so this structure stays.
__global__ __launch_bounds__(256) void k_aggr(const unsigned short* __restrict__ hq,
                                              const int* __restrict__ row_ptr,
                                              const int* __restrict__ col,
                                              const float* __restrict__ qmin,
                                              const float* __restrict__ qmax,
                                              unsigned* __restrict__ tmp) {
  const uint4* hq128 = (const uint4*)hq;     // one row = 8 uint4 (128 B)
  const unsigned* hq32 = (const unsigned*)hq;
  int wv = (blockIdx.x << 2) + (threadIdx.x >> 6);
  int lane = threadIdx.x & 63;
  int grp = lane >> 3;            // edge sub-slot 0..7
  int lo8 = lane & 7;             // which 16 B chunk of the row
  int dw = lane & 31;
  if (wv >= M_PAD) return;
  if (wv >= N_NODES) {
    ((uint2*)(tmp + (size_t)wv * 64))[dw] = make_uint2(0u, 0u);
    return;
  }
  // accumulators: chunk dword k -> ae{k} (dims 4k,4k+2 as u16x2), ao{k} (dims 4k+1,4k+3)
  unsigned ae0 = 0, ae1 = 0, ae2 = 0, ae3 = 0;
  unsigned ao0 = 0, ao1 = 0, ao2 = 0, ao3 = 0;
  int s = __builtin_amdgcn_readfirstlane(row_ptr[wv]);
  int e = __builtin_amdgcn_readfirstlane(row_ptr[wv + 1]);
  int pidx = (lo8 << 3) + grp;    // edge-in-chunk this lane preloads (valid when lo8 < 4)
  for (int base = s; base < e; base += 32) {
    int n = e - base; if (n > 32) n = 32;
    int cv = (pidx < n) ? col[base + pidx] : 0;
    // iteration j: lane gets col of edge 8j+grp  (src lane = (lane&0x38)|j)
    int s0 = __builtin_amdgcn_ds_swizzle(cv, 0x18);   // and=0x18, or=0
    int s1 = __builtin_amdgcn_ds_swizzle(cv, 0x38);   // or=1
    int s2 = __builtin_amdgcn_ds_swizzle(cv, 0x58);   // or=2
    int s3 = __builtin_amdgcn_ds_swizzle(cv, 0x78);   // or=3
    s0 = (grp      < n) ? s0 : N_NODES;
    s1 = (grp +  8 < n) ? s1 : N_NODES;
    s2 = (grp + 16 < n) ? s2 : N_NODES;
    s3 = (grp + 24 < n) ? s3 : N_NODES;
    uint4 v0 = hq128[s0 * 8 + lo8];
    uint4 v1 = hq128[s1 * 8 + lo8];
    uint4 v2 = hq128[s2 * 8 + lo8];
    uint4 v3 = hq128[s3 * 8 + lo8];
    ae0 += v0.x & 0x00FF00FFu; ao0 += (v0.x >> 8) & 0x00FF00FFu;
    ae1 += v0.y & 0x00FF00FFu; ao1 += (v0.y >> 8) & 0x00FF00FFu;
    ae2 += v0.z & 0x00FF00FFu; ao2 += (v0.z >> 8) & 0x00FF00FFu;
    ae3 += v0.w & 0x00FF00FFu; ao3 += (v0.w >> 8) & 0x00FF00FFu;
    ae0 += v1.x & 0x00FF00FFu; ao0 += (v1.x >> 8) & 0x00FF00FFu;
    ae1 += v1.y & 0x00FF00FFu; ao1 += (v1.y >> 8) & 0x00FF00FFu;
    ae2 += v1.z & 0x00FF00FFu; ao2 += (v1.z >> 8) & 0x00FF00FFu;
    ae3 += v1.w & 0x00FF00FFu; ao3 += (v1.w >> 8) & 0x00FF00FFu;
    ae0 += v2.x & 0x00FF00FFu; ao0 += (v2.x >> 8) & 0x00FF00FFu;
    ae1 += v2.y & 0x00FF00FFu; ao1 += (v2.y >> 8) & 0x00FF00FFu;
    ae2 += v2.z & 0x00FF00FFu; ao2 += (v2.z >> 8) & 0x00FF00FFu;
    ae3 += v2.w & 0x00FF00FFu; ao3 += (v2.w >> 8) & 0x00FF00FFu;
    ae0 += v3.x & 0x00FF00FFu; ao0 += (v3.x >> 8) & 0x00FF00FFu;
    ae1 += v3.y & 0x00FF00FFu; ao1 += (v3.y >> 8) & 0x00FF00FFu;
    ae2 += v3.z & 0x00FF00FFu; ao2 += (v3.z >> 8) & 0x00FF00FFu;
    ae3 += v3.w & 0x00FF00FFu; ao3 += (v3.w >> 8) & 0x00FF00FFu;
  }
  // reduce across the 8 edge-slots (lanes differing in bits 3..5)
  ae0 += __shfl_xor(ae0, 8); ae0 += __shfl_xor(ae0, 16); ae0 += __shfl_xor(ae0, 32);
  ae1 += __shfl_xor(ae1, 8); ae1 += __shfl_xor(ae1, 16); ae1 += __shfl_xor(ae1, 32);
  ae2 += __shfl_xor(ae2, 8); ae2 += __shfl_xor(ae2, 16); ae2 += __shfl_xor(ae2, 32);
  ae3 += __shfl_xor(ae3, 8); ae3 += __shfl_xor(ae3, 16); ae3 += __shfl_xor(ae3, 32);
  ao0 += __shfl_xor(ao0, 8); ao0 += __shfl_xor(ao0, 16); ao0 += __shfl_xor(ao0, 32);
  ao1 += __shfl_xor(ao1, 8); ao1 += __shfl_xor(ao1, 16); ao1 += __shfl_xor(ao1, 32);
  ao2 += __shfl_xor(ao2, 8); ao2 += __shfl_xor(ao2, 16); ao2 += __shfl_xor(ao2, 32);
  ao3 += __shfl_xor(ao3, 8); ao3 += __shfl_xor(ao3, 16); ao3 += __shfl_xor(ao3, 32);
  // redistribute to the 32-lane epilogue layout: lane dw wants dword k=dw&3 of chunk dw>>2
  {
    int ba = ((dw >> 2) & 7) << 2;  // byte addr of source lane (holds chunk dw>>2)
    unsigned f0 = (unsigned)__builtin_amdgcn_ds_bpermute(ba, (int)ae0);
    unsigned f1 = (unsigned)__builtin_amdgcn_ds_bpermute(ba, (int)ae1);
    unsigned f2 = (unsigned)__builtin_amdgcn_ds_bpermute(ba, (int)ae2);
    unsigned f3 = (unsigned)__builtin_amdgcn_ds_bpermute(ba, (int)ae3);
    unsigned g0 = (unsigned)__builtin_amdgcn_ds_bpermute(ba, (int)ao0);
    unsigned g1 = (unsigned)__builtin_amdgcn_ds_bpermute(ba, (int)ao1);
    unsigned g2 = (unsigned)__builtin_amdgcn_ds_bpermute(ba, (int)ao2);
    unsigned g3 = (unsigned)__builtin_amdgcn_ds_bpermute(ba, (int)ao3);
    unsigned el = (dw & 1) ? f1 : f0;
    unsigned eh = (dw & 1) ? f3 : f2;
    unsigned ae = (dw & 2) ? eh : el;
    unsigned ol = (dw & 1) ? g1 : g0;
    unsigned oh = (dw & 1) ? g3 : g2;
    unsigned ao = (dw & 2) ? oh : ol;
    if (lane < 32) {
      unsigned v = hq32[wv * 32 + dw];     // self term (eps=0: x + sum_neighbors)
      ae += v & 0x00FF00FFu;
      ao += (v >> 8) & 0x00FF00FFu;
      float cntf = (float)(e - s + 1);
      float4 qn = ((const float4*)qmin)[dw];
      float4 qx = ((const float4*)qmax)[dw];
      const float k255 = 1.0f / 255.0f;
      float A0 = fmaf(qn.x, cntf, (qx.x - qn.x) * k255 * (float)(ae & 0xFFFFu));
      float A1 = fmaf(qn.y, cntf, (qx.y - qn.y) * k255 * (float)(ao & 0xFFFFu));
      float A2 = fmaf(qn.z, cntf, (qx.z - qn.z) * k255 * (float)(ae >> 16));
      float A3 = fmaf(qn.w, cntf, (qx.w - qn.w) * k255 * (float)(ao >> 16));
      ((uint2*)(tmp + (size_t)wv * 64))[dw] = make_uint2(packbf(A0, A1), packbf(A2, A3));
    }
  }
}

// ---------------- fused layer: GEMM1 -> GEMM2 -> pooling (B in regs, z/h in LDS) ----------------
__global__ __launch_bounds__(256, 2) void k_gemm12(const unsigned short* __restrict__ A,
                                                   const unsigned short* __restrict__ Wt1,
                                                   const float* __restrict__ sA1,
                                                   const float* __restrict__ sB1,
                                                   const unsigned short* __restrict__ Wt2,
                                                   const float* __restrict__ sA2,
                                                   const float* __restrict__ sB2,
                                                   const int* __restrict__ batch,
                                                   unsigned short* __restrict__ out,
                                                   float* __restrict__ pooled8, int layer,
                                                   float* __restrict__ pmaxb, int do_max) {
  __shared__ unsigned short zt[4][64][136];   // z then h, wave-private rows
  __shared__ float colred[128];
  __shared__ int sgid[256];
  int w = threadIdx.x >> 6, lane = threadIdx.x & 63;
  int q = lane >> 4, n16 = lane & 15;
  int rbase = (blockIdx.x << 8) + (w << 6);
  if (do_max && threadIdx.x < 128) colred[threadIdx.x] = 0.f;
  {
    int rr = (blockIdx.x << 8) + threadIdx.x;
    sgid[threadIdx.x] = (rr < N_NODES) ? batch[rr] : -1;
  }

  // ---- phase 1: B1 in registers, z -> LDS ----
  {
    bf16x8 Bf[4][8];
#pragma unroll
    for (int ks = 0; ks < 4; ++ks)
#pragma unroll
      for (int c = 0; c < 8; ++c)
        Bf[ks][c] = *(const bf16x8*)(Wt1 + (size_t)((c << 4) + n16) * DIM + ks * 32 + q * 8);
#pragma unroll
    for (int t = 0; t < 4; ++t) {
      int r0 = rbase + (t << 4);
      f32x4 acc[8] = {};
#pragma unroll
      for (int ks = 0; ks < 4; ++ks) {
        bf16x8 a = *(const bf16x8*)(A + (size_t)(r0 + n16) * DIM + ks * 32 + q * 8);
#pragma unroll
        for (int c = 0; c < 8; ++c)
          acc[c] = __builtin_amdgcn_mfma_f32_16x16x32_bf16(a, Bf[ks][c], acc[c], 0, 0, 0);
      }
#pragma unroll
      for (int c = 0; c < 8; ++c) {
        int colc = (c << 4) + n16;
        float s = sA1[colc], tt = sB1[colc];
#pragma unroll
        for (int r = 0; r < 4; ++r) {
          float v = fmaxf(fmaf(s, acc[c][r], tt), 0.0f);
          zt[w][(t << 4) + (q << 2) + r][colc] = f2bf(v);
        }
      }
    }
  }

  // ---- phase 2: B2 in registers, A from LDS; h -> global + LDS ----
  float mcol[8];
#pragma unroll
  for (int c = 0; c < 8; ++c) mcol[c] = 0.f;
  {
    bf16x8 Bf[4][8];
#pragma unroll
    for (int ks = 0; ks < 4; ++ks)
#pragma unroll
      for (int c = 0; c < 8; ++c)
        Bf[ks][c] = *(const bf16x8*)(Wt2 + (size_t)((c << 4) + n16) * DIM + ks * 32 + q * 8);
#pragma unroll
    for (int t = 0; t < 4; ++t) {
      int r0 = rbase + (t << 4);
      f32x4 acc[8] = {};
#pragma unroll
      for (int ks = 0; ks < 4; ++ks) {
        bf16x8 a = *(const bf16x8*)(&zt[w][(t << 4) + n16][ks * 32 + q * 8]);
#pragma unroll
        for (int c = 0; c < 8; ++c)
          acc[c] = __builtin_amdgcn_mfma_f32_16x16x32_bf16(a, Bf[ks][c], acc[c], 0, 0, 0);
      }
      // only LDS ordering needed: zt reads of tile t must finish before overwrite.
      // (previous s_waitcnt(0) also drained vmcnt -> stalled on global stores of
      //  prior tiles; lgkmcnt-only removes that serialization)
      asm volatile("s_waitcnt lgkmcnt(0)" ::: "memory");
#pragma unroll
      for (int c = 0; c < 8; ++c) {
        int colc = (c << 4) + n16;
        float s = sA2[colc], tt = sB2[colc];
#pragma unroll
        for (int r = 0; r < 4; ++r) {
          float v = fmaxf(fmaf(s, acc[c][r], tt), 0.0f);
          mcol[c] = fmaxf(mcol[c], v);
          unsigned short hv = f2bf(v);
          out[(size_t)(r0 + (q << 2) + r) * DIM + colc] = hv;
          zt[w][(t << 4) + (q << 2) + r][colc] = hv;
        }
      }
    }
  }
  __syncthreads();   // h tiles + sgid visible to all

  // ---- pooling: segment-sum sorted rows, one atomic per (segment, col) ----
  {
    const unsigned short* ztf = &zt[0][0][0];
    int colp = threadIdx.x & 127, grp = threadIdx.x >> 7;
    int cp = blockIdx.x & 7;
    float pacc = 0.f;
    int gcur = sgid[grp << 7];
    for (int r = 0; r < 128; ++r) {
      int row = (grp << 7) + r;
      int g = sgid[row];
      if (g != gcur) {
        if (gcur >= 0)
          atomicAdd(&pooled8[((size_t)cp * N_GRAPHS + gcur) * 384 + layer * DIM + colp], pacc);
        pacc = 0.f; gcur = g;
      }
      if (g >= 0) pacc += bfs(ztf[row * 136 + colp]);
    }
    if (gcur >= 0)
      atomicAdd(&pooled8[((size_t)cp * N_GRAPHS + gcur) * 384 + layer * DIM + colp], pacc);
  }

  if (do_max) {
#pragma unroll
    for (int c = 0; c < 8; ++c)
      atomicMax((int*)&colred[(c << 4) + n16], __float_as_int(mcol[c]));
    __syncthreads();
    if (threadIdx.x < 128)
      pmaxb[(size_t)blockIdx.x * 128 + threadIdx.x] = colred[threadIdx.x];
  }
}

// ---------------- head: 8 graphs per block, sums the 8 pooled copies ----------------
__global__ __launch_bounds__(384) void k_head(const float* __restrict__ pooled8,
                                              const float* __restrict__ Wfin,
                                              const float* __restrict__ bfin,
                                              const float* __restrict__ Wout,
                                              const float* __restrict__ bout,
                                              float* __restrict__ out) {
  __shared__ float p[8][384];
  __shared__ float hf[8][392];
  __shared__ float lg[8][10];
  __shared__ float lse[8];
  int t = threadIdx.x, g0 = blockIdx.x << 3;
  for (int i = t; i < 8 * 384; i += 384) {
    int gl = i / 384, k = i % 384;
    float s = 0.f;
#pragma unroll
    for (int cp = 0; cp < 8; ++cp)
      s += pooled8[((size_t)cp * N_GRAPHS + g0 + gl) * 384 + k];
    p[gl][k] = s;
  }
  __syncthreads();
  float bb = bfin[t];
  float acc[8];
#pragma unroll
  for (int g = 0; g < 8; ++g) acc[g] = bb;
  for (int k = 0; k < 384; ++k) {
    float wv = Wfin[k * 384 + t];
#pragma unroll
    for (int g = 0; g < 8; ++g) acc[g] = fmaf(p[g][k], wv, acc[g]);
  }
#pragma unroll
  for (int g = 0; g < 8; ++g) hf[g][t] = fmaxf(acc[g], 0.f);
  __syncthreads();
  if (t < 80) {
    int g = t / 10, c = t % 10;
    float a = bout[c];
    for (int k = 0; k < 384; ++k) a = fmaf(hf[g][k], Wout[k * 10 + c], a);
    lg[g][c] = a;
  }
  __syncthreads();
  if (t < 8) {
    float m = lg[t][0];
#pragma unroll
    for (int i = 1; i < 10; ++i) m = fmaxf(m, lg[t][i]);
    float ss = 0.f;
#pragma unroll
    for (int i = 0; i < 10; ++i) ss += __expf(lg[t][i] - m);
    lse[t] = m + __logf(ss);
  }
  __syncthreads();
  if (t < 80) {
    int g = t / 10, c = t % 10;
    out[(size_t)(g0 + g) * 10 + c] = lg[g][c];
    out[(size_t)N_GRAPHS * 10 + (size_t)(g0 + g) * 10 + c] = lg[g][c] - lse[g];
  }
}

extern "C" void kernel_launch(void* const* d_in, const int* in_sizes, int n_in,
                              void* d_out, int out_size, void* d_ws, size_t ws_size,
                              hipStream_t stream) {
  const float* x     = (const float*)d_in[0];
  const int*   ei    = (const int*)d_in[1];    // [2, N_EDGES]: src then dst
  const int*   batch = (const int*)d_in[2];
  const float* W1    = (const float*)d_in[4];
  const float* b1    = (const float*)d_in[5];
  const float* gamma = (const float*)d_in[6];
  const float* beta  = (const float*)d_in[7];
  const float* rmean = (const float*)d_in[8];
  const float* rvar  = (const float*)d_in[9];
  const float* W2    = (const float*)d_in[10];
  const float* b2    = (const float*)d_in[11];
  const float* Wfin  = (const float*)d_in[12];
  const float* bfin  = (const float*)d_in[13];
  const float* Wout  = (const float*)d_in[14];
  const float* bout  = (const float*)d_in[15];
  float* out = (float*)d_out;

  char* p = (char*)d_ws;
  auto alloc = [&](size_t bytes) { char* r = p; p += (bytes + 255) & ~255ull; return r; };
  int* cnt      = (int*)alloc(NBUCK * 4);
  unsigned* rec = (unsigned*)alloc((size_t)NBUCK * CAP * 4);
  int* bbase    = (int*)alloc((NBUCK + 1) * 4);
  int* row_ptr  = (int*)alloc((N_NODES + 1) * 4);
  int* colb     = (int*)alloc(((size_t)N_EDGES + 256) * 4);
  unsigned short* xq  = (unsigned short*)alloc((size_t)M_PAD * 64 * 2);
  unsigned short* hqb = (unsigned short*)alloc((size_t)M_PAD * 64 * 2);
  unsigned* hbf  = (unsigned*)alloc((size_t)M_PAD * 64 * 4);
  unsigned* tmpb = (unsigned*)alloc((size_t)M_PAD * 64 * 4);
  unsigned short* Wt1 = (unsigned short*)alloc(3 * DIM * DIM * 2);
  unsigned short* Wt2 = (unsigned short*)alloc(3 * DIM * DIM * 2);
  float* pmax   = (float*)alloc((size_t)XMM_NB * 128 * 4);
  float* pmin   = (float*)alloc((size_t)XMM_NB * 128 * 4);
  float* pmaxb  = (float*)alloc((size_t)NGB * 128 * 4);
  float* sA1    = (float*)alloc(384 * 4);
  float* sB1    = (float*)alloc(384 * 4);
  float* sA2    = (float*)alloc(384 * 4);
  float* sB2    = (float*)alloc(384 * 4);
  float* qbuf   = (float*)alloc(1024 * 4);
  float* xmx    = qbuf + 128;    // max(v,0)
  float* xminf  = qbuf + 256;    // min(v,0)
  float* hmax0  = qbuf + 384;
  float* hmax1  = qbuf + 512;
  float* zeros  = qbuf + 640;    // 128 zeros (qmin for relu'd h)
  float* pooled8 = (float*)alloc((size_t)NPOOL * 4);

  k_zeroall<<<(NPOOL + 255) / 256, 256, 0, stream>>>(cnt, (int*)qbuf, (int*)pooled8);

  // CSR build via tiled-reservation counting sort (edges constant across layers)
  k_bucket<<<NTILE, 256, 0, stream>>>(ei, cnt, rec);
  k_bscan<<<1, 512, 0, stream>>>(cnt, bbase, row_ptr);
  k_build<<<NBUCK, 256, 0, stream>>>(rec, cnt, bbase, row_ptr, colb);

  k_xmm1<<<XMM_NB, 256, 0, stream>>>(x, pmax, pmin);
  k_xmm2<<<256, 64, 0, stream>>>(pmax, pmin, xmx, xminf);
  k_convx<<<(M_PAD * 64 + 255) / 256, 256, 0, stream>>>(x, xminf, xmx, xq);
  k_convw<<<(3 * DIM * DIM + 255) / 256, 256, 0, stream>>>(W1, W2, Wt1, Wt2);
  k_coef<<<3, 128, 0, stream>>>(b1, gamma, beta, rmean, rvar, b2, sA1, sB1, sA2, sB2);

  // layer 0
  k_aggr<<<M_PAD / 4, 256, 0, stream>>>(xq, row_ptr, colb, xminf, xmx, tmpb);
  k_gemm12<<<NGB, 256, 0, stream>>>((const unsigned short*)tmpb, Wt1, sA1, sB1,
                                    Wt2, sA2, sB2, batch, (unsigned short*)hbf,
                                    pooled8, 0, pmaxb, 1);
  k_hred<<<128, 64, 0, stream>>>(pmaxb, hmax0);
  k_quant<<<(M_PAD * 64 + 255) / 256, 256, 0, stream>>>(hbf, hmax0, hqb);
  // layer 1
  k_aggr<<<M_PAD / 4, 256, 0, stream>>>(hqb, row_ptr, colb, zeros, hmax0, tmpb);
  k_gemm12<<<NGB, 256, 0, stream>>>((const unsigned short*)tmpb, Wt1 + DIM * DIM,
                                    sA1 + DIM, sB1 + DIM, Wt2 + DIM * DIM,
                                    sA2 + DIM, sB2 + DIM, batch, (unsigned short*)hbf,
                                    pooled8, 1, pmaxb, 1);
  k_hred<<<128, 64, 0, stream>>>(pmaxb, hmax1);
  k_quant<<<(M_PAD * 64 + 255) / 256, 256, 0, stream>>>(hbf, hmax1, hqb);
  // layer 2 (h never gathered again: no max/quant)
  k_aggr<<<M_PAD / 4, 256, 0, stream>>>(hqb, row_ptr, colb, zeros, hmax1, tmpb);
  k_gemm12<<<NGB, 256, 0, stream>>>((const unsigned short*)tmpb, Wt1 + 2 * DIM * DIM,
                                    sA1 + 2 * DIM, sB1 + 2 * DIM, Wt2 + 2 * DIM * DIM,
                                    sA2 + 2 * DIM, sB2 + 2 * DIM, batch, (unsigned short*)hbf,
                                    pooled8, 2, pmaxb, 0);

  k_head<<<N_GRAPHS / 8, 384, 0, stream>>>(pooled8, Wfin, bfin, Wout, bout, out);
}

// Round 5
// 578.197 us; speedup vs baseline: 1.9545x; 1.0422x over previous
//
#include <hip/hip_runtime.h>
#include <stdint.h>

#define N_NODES 100000
#define N_EDGES 3200000
#define N_GRAPHS 512
#define DIM 128
#define M_PAD 100096          // N_NODES padded to multiple of 64
#define NGB (M_PAD / 256)     // 391 gemm blocks (256 rows each)
#define NBUCK 391             // buckets of 256 dst nodes: 391*256 = 100096 >= 100000
#define CAP 9216              // per-bucket region capacity; mean ~8184, sigma ~90
#define TILE 4096             // edges per block in k_bucket
#define NTILE 782             // ceil(3.2M / 4096)
#define XMM_NB 392            // stage-1 blocks for x min/max
#define NPOOL (8 * N_GRAPHS * 384)

typedef __bf16 bf16x8 __attribute__((ext_vector_type(8)));
typedef float f32x4 __attribute__((ext_vector_type(4)));

__device__ __forceinline__ unsigned short f2bf(float f) {
  unsigned u = __float_as_uint(f);
  u = u + 0x7FFFu + ((u >> 16) & 1u);      // round-to-nearest-even
  return (unsigned short)(u >> 16);
}
__device__ __forceinline__ float bflo(unsigned v) { return __uint_as_float(v << 16); }
__device__ __forceinline__ float bfhi(unsigned v) { return __uint_as_float(v & 0xFFFF0000u); }
__device__ __forceinline__ float bfs(unsigned short v) { return __uint_as_float(((unsigned)v) << 16); }
__device__ __forceinline__ unsigned packbf(float a, float b) {
  return (unsigned)f2bf(a) | ((unsigned)f2bf(b) << 16);
}

// ---------------- combined zeroing (one launch) ----------------
__global__ void k_zeroall(int* __restrict__ cnt, int* __restrict__ qbuf,
                          int* __restrict__ pooled) {
  int i = blockIdx.x * 256 + threadIdx.x;
  if (i < NBUCK) cnt[i] = 0;
  if (i < 1024) qbuf[i] = 0;
  if (i < NPOOL) pooled[i] = 0;
}

// ---------------- CSR build: tiled-reservation counting sort ----------------
__global__ __launch_bounds__(256) void k_bucket(const int* __restrict__ ei,
                                                int* __restrict__ cnt,
                                                unsigned* __restrict__ rec) {
  __shared__ int hist[NBUCK];
  __shared__ int curs[NBUCK];
  int t = threadIdx.x;
  int base_e = blockIdx.x * TILE;
  int es[16], ed[16];
#pragma unroll
  for (int k = 0; k < 16; ++k) {
    int e = base_e + k * 256 + t;
    if (e < N_EDGES) { es[k] = ei[e]; ed[k] = ei[N_EDGES + e]; }
    else ed[k] = -1;
  }
  for (int i = t; i < NBUCK; i += 256) hist[i] = 0;
  __syncthreads();
#pragma unroll
  for (int k = 0; k < 16; ++k)
    if (ed[k] >= 0) atomicAdd(&hist[ed[k] >> 8], 1);
  __syncthreads();
  for (int i = t; i < NBUCK; i += 256) {
    int h = hist[i];
    int g = h ? atomicAdd(&cnt[i], h) : 0;
    curs[i] = i * CAP + g;
  }
  __syncthreads();
#pragma unroll
  for (int k = 0; k < 16; ++k) {
    if (ed[k] >= 0) {
      int b = ed[k] >> 8;
      int pos = atomicAdd(&curs[b], 1);
      rec[pos] = ((unsigned)es[k] << 8) | (unsigned)(ed[k] & 255);
    }
  }
}

__global__ __launch_bounds__(512) void k_bscan(const int* __restrict__ cnt,
                                               int* __restrict__ bbase,
                                               int* __restrict__ row_ptr) {
  __shared__ int sc[512];
  int t = threadIdx.x;
  int tot = (t < NBUCK) ? min(cnt[t], CAP) : 0;
  sc[t] = tot; __syncthreads();
  for (int off = 1; off < 512; off <<= 1) {
    int x = (t >= off) ? sc[t - off] : 0;
    __syncthreads();
    sc[t] += x;
    __syncthreads();
  }
  if (t < NBUCK) bbase[t] = sc[t] - tot;                 // exclusive
  if (t == NBUCK - 1) {
    bbase[NBUCK] = sc[t];
    row_ptr[N_NODES] = sc[t];                            // == N_EDGES
  }
}

__global__ __launch_bounds__(256) void k_build(const unsigned* __restrict__ rec,
                                               const int* __restrict__ cnt,
                                               const int* __restrict__ bbase,
                                               int* __restrict__ row_ptr,
                                               int* __restrict__ col) {
  __shared__ int hist[256];
  __shared__ int sc[256];
  __shared__ int curs[256];
  int b = blockIdx.x, t = threadIdx.x;
  int n = min(cnt[b], CAP);
  const unsigned* p = rec + (size_t)b * CAP;
  hist[t] = 0; __syncthreads();
  for (int i = t; i < n; i += 256) atomicAdd(&hist[p[i] & 255u], 1);
  __syncthreads();
  int v = hist[t];
  sc[t] = v; __syncthreads();
  for (int off = 1; off < 256; off <<= 1) {
    int x = (t >= off) ? sc[t - off] : 0;
    __syncthreads();
    sc[t] += x;
    __syncthreads();
  }
  int excl = bbase[b] + sc[t] - v;
  int node = (b << 8) + t;
  if (node < N_NODES) row_ptr[node] = excl;
  curs[t] = excl;
  __syncthreads();
  for (int i = t; i < n; i += 256) {
    unsigned w = p[i];
    int pos = atomicAdd(&curs[w & 255u], 1);
    col[pos] = (int)(w >> 8);
  }
}

// ---------------- x per-column range: two-stage reduction ----------------
__global__ __launch_bounds__(256) void k_xmm1(const float* __restrict__ x,
                                              float* __restrict__ pmax,
                                              float* __restrict__ pmin) {
  __shared__ float smx[8][32][4];
  __shared__ float smn[8][32][4];
  int t = threadIdx.x;
  int c4 = t & 31;          // float4 column group
  int ro = t >> 5;          // 0..7
  float mx0 = 0.f, mx1 = 0.f, mx2 = 0.f, mx3 = 0.f;
  float mn0 = 0.f, mn1 = 0.f, mn2 = 0.f, mn3 = 0.f;
  for (int row = blockIdx.x * 8 + ro; row < N_NODES; row += XMM_NB * 8) {
    float4 v = ((const float4*)x)[(size_t)row * 32 + c4];
    mx0 = fmaxf(mx0, v.x); mn0 = fmaxf(mn0, -v.x);
    mx1 = fmaxf(mx1, v.y); mn1 = fmaxf(mn1, -v.y);
    mx2 = fmaxf(mx2, v.z); mn2 = fmaxf(mn2, -v.z);
    mx3 = fmaxf(mx3, v.w); mn3 = fmaxf(mn3, -v.w);
  }
  smx[ro][c4][0] = mx0; smx[ro][c4][1] = mx1; smx[ro][c4][2] = mx2; smx[ro][c4][3] = mx3;
  smn[ro][c4][0] = mn0; smn[ro][c4][1] = mn1; smn[ro][c4][2] = mn2; smn[ro][c4][3] = mn3;
  __syncthreads();
  for (int off = 4; off > 0; off >>= 1) {
    if (ro < off) {
#pragma unroll
      for (int k = 0; k < 4; ++k) {
        smx[ro][c4][k] = fmaxf(smx[ro][c4][k], smx[ro + off][c4][k]);
        smn[ro][c4][k] = fmaxf(smn[ro][c4][k], smn[ro + off][c4][k]);
      }
    }
    __syncthreads();
  }
  if (ro == 0) {
#pragma unroll
    for (int k = 0; k < 4; ++k) {
      pmax[blockIdx.x * 128 + c4 * 4 + k] = smx[0][c4][k];
      pmin[blockIdx.x * 128 + c4 * 4 + k] = smn[0][c4][k];
    }
  }
}

__global__ __launch_bounds__(64) void k_xmm2(const float* __restrict__ pmax,
                                             const float* __restrict__ pmin,
                                             float* __restrict__ xmx,
                                             float* __restrict__ xminf) {
  int c = blockIdx.x & 127;
  int isMin = blockIdx.x >> 7;
  const float* src = isMin ? pmin : pmax;
  int l = threadIdx.x;
  float m = 0.f;
  for (int p2 = l; p2 < XMM_NB; p2 += 64) m = fmaxf(m, src[p2 * 128 + c]);
#pragma unroll
  for (int off = 32; off > 0; off >>= 1) m = fmaxf(m, __shfl_down(m, off));
  if (l == 0) {
    if (isMin) xminf[c] = -m;
    else xmx[c] = m;
  }
}

// ---------------- conversions / coefficients ----------------
// vectorized x2: one float4 (4 dims) -> one u32 (4 u8) per thread
__global__ void k_convx(const float* __restrict__ x, const float* __restrict__ qmin,
                        const float* __restrict__ qmax, unsigned short* __restrict__ xq) {
  int j = blockIdx.x * 256 + threadIdx.x;
  if (j >= M_PAD * 32) return;
  int k = j & 31;            // float4 group within row
  int node = j >> 5;
  unsigned o = 0;
  if (node < N_NODES) {
    float4 f = ((const float4*)x)[j];
    float4 mn = ((const float4*)qmin)[k];
    float4 mx = ((const float4*)qmax)[k];
    float r0 = mx.x - mn.x, r1 = mx.y - mn.y, r2 = mx.z - mn.z, r3 = mx.w - mn.w;
    float is0 = r0 > 1e-20f ? 255.f / r0 : 0.f;
    float is1 = r1 > 1e-20f ? 255.f / r1 : 0.f;
    float is2 = r2 > 1e-20f ? 255.f / r2 : 0.f;
    float is3 = r3 > 1e-20f ? 255.f / r3 : 0.f;
    int q0 = (int)rintf((f.x - mn.x) * is0); q0 = min(max(q0, 0), 255);
    int q1 = (int)rintf((f.y - mn.y) * is1); q1 = min(max(q1, 0), 255);
    int q2 = (int)rintf((f.z - mn.z) * is2); q2 = min(max(q2, 0), 255);
    int q3 = (int)rintf((f.w - mn.w) * is3); q3 = min(max(q3, 0), 255);
    o = (unsigned)q0 | ((unsigned)q1 << 8) | ((unsigned)q2 << 16) | ((unsigned)q3 << 24);
  }
  ((unsigned*)xq)[j] = o;
}

__device__ __forceinline__ unsigned q1dw(unsigned v, float is0, float is1) {
  int q0 = (int)rintf(bflo(v) * is0); q0 = min(max(q0, 0), 255);
  int q1 = (int)rintf(bfhi(v) * is1); q1 = min(max(q1, 0), 255);
  return (unsigned)(q0 | (q1 << 8));
}

// h (bf16x2-packed) -> u8 (min = 0); vectorized x4 (uint4 in, uint2 out).
// Padding rows forced to ZERO so k_aggr can gather row N_NODES for masked tails.
__global__ void k_quant(const unsigned* __restrict__ hbf, const float* __restrict__ qmax,
                        unsigned short* __restrict__ hq) {
  int j = blockIdx.x * 256 + threadIdx.x;
  if (j >= M_PAD * 16) return;
  int node = j >> 4;
  uint2 o = make_uint2(0u, 0u);
  if (node < N_NODES) {
    int k = j & 15;                       // 8-dim group within row
    uint4 v = ((const uint4*)hbf)[j];
    float4 mxa = ((const float4*)qmax)[2 * k];
    float4 mxb = ((const float4*)qmax)[2 * k + 1];
    float ia0 = mxa.x > 1e-20f ? 255.f / mxa.x : 0.f;
    float ia1 = mxa.y > 1e-20f ? 255.f / mxa.y : 0.f;
    float ia2 = mxa.z > 1e-20f ? 255.f / mxa.z : 0.f;
    float ia3 = mxa.w > 1e-20f ? 255.f / mxa.w : 0.f;
    float ib0 = mxb.x > 1e-20f ? 255.f / mxb.x : 0.f;
    float ib1 = mxb.y > 1e-20f ? 255.f / mxb.y : 0.f;
    float ib2 = mxb.z > 1e-20f ? 255.f / mxb.z : 0.f;
    float ib3 = mxb.w > 1e-20f ? 255.f / mxb.w : 0.f;
    o.x = q1dw(v.x, ia0, ia1) | (q1dw(v.y, ia2, ia3) << 16);
    o.y = q1dw(v.z, ib0, ib1) | (q1dw(v.w, ib2, ib3) << 16);
  }
  ((uint2*)hq)[j] = o;
}

__global__ void k_convw(const float* __restrict__ W1, const float* __restrict__ W2,
                        unsigned short* __restrict__ Wt1, unsigned short* __restrict__ Wt2) {
  int i = blockIdx.x * 256 + threadIdx.x;
  if (i >= 3 * DIM * DIM) return;
  int l = i >> 14, rem = i & 16383, k = rem >> 7, n = rem & 127;
  int o = (l << 14) + (n << 7) + k;          // transposed: Wt[l][n][k]
  Wt1[o] = f2bf(W1[i]);
  Wt2[o] = f2bf(W2[i]);
}

__global__ void k_coef(const float* __restrict__ b1, const float* __restrict__ gamma,
                       const float* __restrict__ beta, const float* __restrict__ rmean,
                       const float* __restrict__ rvar, const float* __restrict__ b2,
                       float* __restrict__ sA1, float* __restrict__ sB1,
                       float* __restrict__ sA2, float* __restrict__ sB2) {
  int i = blockIdx.x * 128 + threadIdx.x;
  if (i >= 3 * DIM) return;
  float sa = gamma[i] * rsqrtf(rvar[i] + 1e-5f);
  sA1[i] = sa;
  sB1[i] = fmaf(sa, b1[i] - rmean[i], beta[i]);  // sa*(b1-rmean)+beta
  sA2[i] = 1.0f;
  sB2[i] = b2[i];
}

// ---------------- aggregation v4 (u8): dwordx4 gathers, 8 edges per VMEM instr ----------------
// v4 is the measured best (57 us).  Law from v4/v5/v6: dur = FETCH_SIZE / ~2.8-3.2 TB/s
// (scattered L2-fill ceiling, insensitive to ILP/occupancy); v4's FETCH (~158 MB) is
// within ~20% of the per-XCD compulsory floor for a random graph, so this stays.
__global__ __launch_bounds__(256) void k_aggr(const unsigned short* __restrict__ hq,
                                              const int* __restrict__ row_ptr,
                                              const int* __restrict__ col,
                                              const float* __restrict__ qmin,
                                              const float* __restrict__ qmax,
                                              unsigned* __restrict__ tmp) {
  const uint4* hq128 = (const uint4*)hq;     // one row = 8 uint4 (128 B)
  const unsigned* hq32 = (const unsigned*)hq;
  int wv = (blockIdx.x << 2) + (threadIdx.x >> 6);
  int lane = threadIdx.x & 63;
  int grp = lane >> 3;            // edge sub-slot 0..7
  int lo8 = lane & 7;             // which 16 B chunk of the row
  int dw = lane & 31;
  if (wv >= M_PAD) return;
  if (wv >= N_NODES) {
    ((uint2*)(tmp + (size_t)wv * 64))[dw] = make_uint2(0u, 0u);
    return;
  }
  // accumulators: chunk dword k -> ae{k} (dims 4k,4k+2 as u16x2), ao{k} (dims 4k+1,4k+3)
  unsigned ae0 = 0, ae1 = 0, ae2 = 0, ae3 = 0;
  unsigned ao0 = 0, ao1 = 0, ao2 = 0, ao3 = 0;
  int s = __builtin_amdgcn_readfirstlane(row_ptr[wv]);
  int e = __builtin_amdgcn_readfirstlane(row_ptr[wv + 1]);
  int pidx = (lo8 << 3) + grp;    // edge-in-chunk this lane preloads (valid when lo8 < 4)
  for (int base = s; base < e; base += 32) {
    int n = e - base; if (n > 32) n = 32;
    int cv = (pidx < n) ? col[base + pidx] : 0;
    // iteration j: lane gets col of edge 8j+grp  (src lane = (lane&0x38)|j)
    int s0 = __builtin_amdgcn_ds_swizzle(cv, 0x18);   // and=0x18, or=0
    int s1 = __builtin_amdgcn_ds_swizzle(cv, 0x38);   // or=1
    int s2 = __builtin_amdgcn_ds_swizzle(cv, 0x58);   // or=2
    int s3 = __builtin_amdgcn_ds_swizzle(cv, 0x78);   // or=3
    s0 = (grp      < n) ? s0 : N_NODES;
    s1 = (grp +  8 < n) ? s1 : N_NODES;
    s2 = (grp + 16 < n) ? s2 : N_NODES;
    s3 = (grp + 24 < n) ? s3 : N_NODES;
    uint4 v0 = hq128[s0 * 8 + lo8];
    uint4 v1 = hq128[s1 * 8 + lo8];
    uint4 v2 = hq128[s2 * 8 + lo8];
    uint4 v3 = hq128[s3 * 8 + lo8];
    ae0 += v0.x & 0x00FF00FFu; ao0 += (v0.x >> 8) & 0x00FF00FFu;
    ae1 += v0.y & 0x00FF00FFu; ao1 += (v0.y >> 8) & 0x00FF00FFu;
    ae2 += v0.z & 0x00FF00FFu; ao2 += (v0.z >> 8) & 0x00FF00FFu;
    ae3 += v0.w & 0x00FF00FFu; ao3 += (v0.w >> 8) & 0x00FF00FFu;
    ae0 += v1.x & 0x00FF00FFu; ao0 += (v1.x >> 8) & 0x00FF00FFu;
    ae1 += v1.y & 0x00FF00FFu; ao1 += (v1.y >> 8) & 0x00FF00FFu;
    ae2 += v1.z & 0x00FF00FFu; ao2 += (v1.z >> 8) & 0x00FF00FFu;
    ae3 += v1.w & 0x00FF00FFu; ao3 += (v1.w >> 8) & 0x00FF00FFu;
    ae0 += v2.x & 0x00FF00FFu; ao0 += (v2.x >> 8) & 0x00FF00FFu;
    ae1 += v2.y & 0x00FF00FFu; ao1 += (v2.y >> 8) & 0x00FF00FFu;
    ae2 += v2.z & 0x00FF00FFu; ao2 += (v2.z >> 8) & 0x00FF00FFu;
    ae3 += v2.w & 0x00FF00FFu; ao3 += (v2.w >> 8) & 0x00FF00FFu;
    ae0 += v3.x & 0x00FF00FFu; ao0 += (v3.x >> 8) & 0x00FF00FFu;
    ae1 += v3.y & 0x00FF00FFu; ao1 += (v3.y >> 8) & 0x00FF00FFu;
    ae2 += v3.z & 0x00FF00FFu; ao2 += (v3.z >> 8) & 0x00FF00FFu;
    ae3 += v3.w & 0x00FF00FFu; ao3 += (v3.w >> 8) & 0x00FF00FFu;
  }
  // reduce across the 8 edge-slots (lanes differing in bits 3..5)
  ae0 += __shfl_xor(ae0, 8); ae0 += __shfl_xor(ae0, 16); ae0 += __shfl_xor(ae0, 32);
  ae1 += __shfl_xor(ae1, 8); ae1 += __shfl_xor(ae1, 16); ae1 += __shfl_xor(ae1, 32);
  ae2 += __shfl_xor(ae2, 8); ae2 += __shfl_xor(ae2, 16); ae2 += __shfl_xor(ae2, 32);
  ae3 += __shfl_xor(ae3, 8); ae3 += __shfl_xor(ae3, 16); ae3 += __shfl_xor(ae3, 32);
  ao0 += __shfl_xor(ao0, 8); ao0 += __shfl_xor(ao0, 16); ao0 += __shfl_xor(ao0, 32);
  ao1 += __shfl_xor(ao1, 8); ao1 += __shfl_xor(ao1, 16); ao1 += __shfl_xor(ao1, 32);
  ao2 += __shfl_xor(ao2, 8); ao2 += __shfl_xor(ao2, 16); ao2 += __shfl_xor(ao2, 32);
  ao3 += __shfl_xor(ao3, 8); ao3 += __shfl_xor(ao3, 16); ao3 += __shfl_xor(ao3, 32);
  // redistribute to the 32-lane epilogue layout: lane dw wants dword k=dw&3 of chunk dw>>2
  {
    int ba = ((dw >> 2) & 7) << 2;  // byte addr of source lane (holds chunk dw>>2)
    unsigned f0 = (unsigned)__builtin_amdgcn_ds_bpermute(ba, (int)ae0);
    unsigned f1 = (unsigned)__builtin_amdgcn_ds_bpermute(ba, (int)ae1);
    unsigned f2 = (unsigned)__builtin_amdgcn_ds_bpermute(ba, (int)ae2);
    unsigned f3 = (unsigned)__builtin_amdgcn_ds_bpermute(ba, (int)ae3);
    unsigned g0 = (unsigned)__builtin_amdgcn_ds_bpermute(ba, (int)ao0);
    unsigned g1 = (unsigned)__builtin_amdgcn_ds_bpermute(ba, (int)ao1);
    unsigned g2 = (unsigned)__builtin_amdgcn_ds_bpermute(ba, (int)ao2);
    unsigned g3 = (unsigned)__builtin_amdgcn_ds_bpermute(ba, (int)ao3);
    unsigned el = (dw & 1) ? f1 : f0;
    unsigned eh = (dw & 1) ? f3 : f2;
    unsigned ae = (dw & 2) ? eh : el;
    unsigned ol = (dw & 1) ? g1 : g0;
    unsigned oh = (dw & 1) ? g3 : g2;
    unsigned ao = (dw & 2) ? oh : ol;
    if (lane < 32) {
      unsigned v = hq32[wv * 32 + dw];     // self term (eps=0: x + sum_neighbors)
      ae += v & 0x00FF00FFu;
      ao += (v >> 8) & 0x00FF00FFu;
      float cntf = (float)(e - s + 1);
      float4 qn = ((const float4*)qmin)[dw];
      float4 qx = ((const float4*)qmax)[dw];
      const float k255 = 1.0f / 255.0f;
      float A0 = fmaf(qn.x, cntf, (qx.x - qn.x) * k255 * (float)(ae & 0xFFFFu));
      float A1 = fmaf(qn.y, cntf, (qx.y - qn.y) * k255 * (float)(ao & 0xFFFFu));
      float A2 = fmaf(qn.z, cntf, (qx.z - qn.z) * k255 * (float)(ae >> 16));
      float A3 = fmaf(qn.w, cntf, (qx.w - qn.w) * k255 * (float)(ao >> 16));
      ((uint2*)(tmp + (size_t)wv * 64))[dw] = make_uint2(packbf(A0, A1), packbf(A2, A3));
    }
  }
}

// ---------------- fused layer: GEMM1 -> GEMM2 -> pooling (B in regs, z/h in LDS) ----------------
// h store: bulk coalesced copy from LDS after sync (1 KB/instr) instead of 32 scalar
// u16 stores/thread; skipped entirely on the last layer (h never re-read).
// hmax: per-block column max -> device-scope atomicMax (f32>=0 as int), replaces k_hred.
__global__ __launch_bounds__(256, 2) void k_gemm12(const unsigned short* __restrict__ A,
                                                   const unsigned short* __restrict__ Wt1,
                                                   const float* __restrict__ sA1,
                                                   const float* __restrict__ sB1,
                                                   const unsigned short* __restrict__ Wt2,
                                                   const float* __restrict__ sA2,
                                                   const float* __restrict__ sB2,
                                                   const int* __restrict__ batch,
                                                   unsigned short* __restrict__ out,
                                                   float* __restrict__ pooled8, int layer,
                                                   float* __restrict__ hmax, int do_max) {
  __shared__ unsigned short zt[4][64][136];   // z then h, wave-private rows
  __shared__ float colred[128];
  __shared__ int sgid[256];
  int w = threadIdx.x >> 6, lane = threadIdx.x & 63;
  int q = lane >> 4, n16 = lane & 15;
  int rbase = (blockIdx.x << 8) + (w << 6);
  if (do_max && threadIdx.x < 128) colred[threadIdx.x] = 0.f;
  {
    int rr = (blockIdx.x << 8) + threadIdx.x;
    sgid[threadIdx.x] = (rr < N_NODES) ? batch[rr] : -1;
  }

  // ---- phase 1: B1 in registers, z -> LDS ----
  {
    bf16x8 Bf[4][8];
#pragma unroll
    for (int ks = 0; ks < 4; ++ks)
#pragma unroll
      for (int c = 0; c < 8; ++c)
        Bf[ks][c] = *(const bf16x8*)(Wt1 + (size_t)((c << 4) + n16) * DIM + ks * 32 + q * 8);
#pragma unroll
    for (int t = 0; t < 4; ++t) {
      int r0 = rbase + (t << 4);
      f32x4 acc[8] = {};
#pragma unroll
      for (int ks = 0; ks < 4; ++ks) {
        bf16x8 a = *(const bf16x8*)(A + (size_t)(r0 + n16) * DIM + ks * 32 + q * 8);
#pragma unroll
        for (int c = 0; c < 8; ++c)
          acc[c] = __builtin_amdgcn_mfma_f32_16x16x32_bf16(a, Bf[ks][c], acc[c], 0, 0, 0);
      }
#pragma unroll
      for (int c = 0; c < 8; ++c) {
        int colc = (c << 4) + n16;
        float s = sA1[colc], tt = sB1[colc];
#pragma unroll
        for (int r = 0; r < 4; ++r) {
          float v = fmaxf(fmaf(s, acc[c][r], tt), 0.0f);
          zt[w][(t << 4) + (q << 2) + r][colc] = f2bf(v);
        }
      }
    }
  }

  // ---- phase 2: B2 in registers, A from LDS; h -> LDS ----
  float mcol[8];
#pragma unroll
  for (int c = 0; c < 8; ++c) mcol[c] = 0.f;
  {
    bf16x8 Bf[4][8];
#pragma unroll
    for (int ks = 0; ks < 4; ++ks)
#pragma unroll
      for (int c = 0; c < 8; ++c)
        Bf[ks][c] = *(const bf16x8*)(Wt2 + (size_t)((c << 4) + n16) * DIM + ks * 32 + q * 8);
#pragma unroll
    for (int t = 0; t < 4; ++t) {
      int r0 = rbase + (t << 4);
      f32x4 acc[8] = {};
#pragma unroll
      for (int ks = 0; ks < 4; ++ks) {
        bf16x8 a = *(const bf16x8*)(&zt[w][(t << 4) + n16][ks * 32 + q * 8]);
#pragma unroll
        for (int c = 0; c < 8; ++c)
          acc[c] = __builtin_amdgcn_mfma_f32_16x16x32_bf16(a, Bf[ks][c], acc[c], 0, 0, 0);
      }
      // only LDS ordering needed: zt reads of tile t must finish before overwrite
      asm volatile("s_waitcnt lgkmcnt(0)" ::: "memory");
#pragma unroll
      for (int c = 0; c < 8; ++c) {
        int colc = (c << 4) + n16;
        float s = sA2[colc], tt = sB2[colc];
#pragma unroll
        for (int r = 0; r < 4; ++r) {
          float v = fmaxf(fmaf(s, acc[c][r], tt), 0.0f);
          mcol[c] = fmaxf(mcol[c], v);
          zt[w][(t << 4) + (q << 2) + r][colc] = f2bf(v);
        }
      }
    }
  }
  __syncthreads();   // h tiles + sgid visible to all

  // ---- bulk coalesced h store (only when a later layer re-reads h) ----
  if (do_max) {
    const unsigned short* ztf = &zt[0][0][0];
    int chunk = threadIdx.x & 15;          // 16 B chunk within a 256 B row
    int rsub  = threadIdx.x >> 4;          // 0..15
    unsigned short* ob = out + ((size_t)blockIdx.x << 8) * DIM;
#pragma unroll
    for (int i = 0; i < 16; ++i) {
      int r = (i << 4) + rsub;             // 0..255
      uint4 v = *(const uint4*)(ztf + r * 136 + chunk * 8);
      *(uint4*)(ob + r * DIM + chunk * 8) = v;
    }
  }

  // ---- pooling: segment-sum sorted rows, one atomic per (segment, col) ----
  {
    const unsigned short* ztf = &zt[0][0][0];
    int colp = threadIdx.x & 127, grp = threadIdx.x >> 7;
    int cp = blockIdx.x & 7;
    float pacc = 0.f;
    int gcur = sgid[grp << 7];
    for (int r = 0; r < 128; ++r) {
      int row = (grp << 7) + r;
      int g = sgid[row];
      if (g != gcur) {
        if (gcur >= 0)
          atomicAdd(&pooled8[((size_t)cp * N_GRAPHS + gcur) * 384 + layer * DIM + colp], pacc);
        pacc = 0.f; gcur = g;
      }
      if (g >= 0) pacc += bfs(ztf[row * 136 + colp]);
    }
    if (gcur >= 0)
      atomicAdd(&pooled8[((size_t)cp * N_GRAPHS + gcur) * 384 + layer * DIM + colp], pacc);
  }

  if (do_max) {
#pragma unroll
    for (int c = 0; c < 8; ++c)
      atomicMax((int*)&colred[(c << 4) + n16], __float_as_int(mcol[c]));
    __syncthreads();
    if (threadIdx.x < 128)
      atomicMax((int*)&hmax[threadIdx.x], __float_as_int(colred[threadIdx.x]));
  }
}

// ---------------- head: 8 graphs per block, sums the 8 pooled copies ----------------
__global__ __launch_bounds__(384) void k_head(const float* __restrict__ pooled8,
                                              const float* __restrict__ Wfin,
                                              const float* __restrict__ bfin,
                                              const float* __restrict__ Wout,
                                              const float* __restrict__ bout,
                                              float* __restrict__ out) {
  __shared__ float p[8][384];
  __shared__ float hf[8][392];
  __shared__ float lg[8][10];
  __shared__ float lse[8];
  int t = threadIdx.x, g0 = blockIdx.x << 3;
  for (int i = t; i < 8 * 384; i += 384) {
    int gl = i / 384, k = i % 384;
    float s = 0.f;
#pragma unroll
    for (int cp = 0; cp < 8; ++cp)
      s += pooled8[((size_t)cp * N_GRAPHS + g0 + gl) * 384 + k];
    p[gl][k] = s;
  }
  __syncthreads();
  float bb = bfin[t];
  float acc[8];
#pragma unroll
  for (int g = 0; g < 8; ++g) acc[g] = bb;
  for (int k = 0; k < 384; ++k) {
    float wv = Wfin[k * 384 + t];
#pragma unroll
    for (int g = 0; g < 8; ++g) acc[g] = fmaf(p[g][k], wv, acc[g]);
  }
#pragma unroll
  for (int g = 0; g < 8; ++g) hf[g][t] = fmaxf(acc[g], 0.f);
  __syncthreads();
  if (t < 80) {
    int g = t / 10, c = t % 10;
    float a = bout[c];
    for (int k = 0; k < 384; ++k) a = fmaf(hf[g][k], Wout[k * 10 + c], a);
    lg[g][c] = a;
  }
  __syncthreads();
  if (t < 8) {
    float m = lg[t][0];
#pragma unroll
    for (int i = 1; i < 10; ++i) m = fmaxf(m, lg[t][i]);
    float ss = 0.f;
#pragma unroll
    for (int i = 0; i < 10; ++i) ss += __expf(lg[t][i] - m);
    lse[t] = m + __logf(ss);
  }
  __syncthreads();
  if (t < 80) {
    int g = t / 10, c = t % 10;
    out[(size_t)(g0 + g) * 10 + c] = lg[g][c];
    out[(size_t)N_GRAPHS * 10 + (size_t)(g0 + g) * 10 + c] = lg[g][c] - lse[g];
  }
}

extern "C" void kernel_launch(void* const* d_in, const int* in_sizes, int n_in,
                              void* d_out, int out_size, void* d_ws, size_t ws_size,
                              hipStream_t stream) {
  const float* x     = (const float*)d_in[0];
  const int*   ei    = (const int*)d_in[1];    // [2, N_EDGES]: src then dst
  const int*   batch = (const int*)d_in[2];
  const float* W1    = (const float*)d_in[4];
  const float* b1    = (const float*)d_in[5];
  const float* gamma = (const float*)d_in[6];
  const float* beta  = (const float*)d_in[7];
  const float* rmean = (const float*)d_in[8];
  const float* rvar  = (const float*)d_in[9];
  const float* W2    = (const float*)d_in[10];
  const float* b2    = (const float*)d_in[11];
  const float* Wfin  = (const float*)d_in[12];
  const float* bfin  = (const float*)d_in[13];
  const float* Wout  = (const float*)d_in[14];
  const float* bout  = (const float*)d_in[15];
  float* out = (float*)d_out;

  char* p = (char*)d_ws;
  auto alloc = [&](size_t bytes) { char* r = p; p += (bytes + 255) & ~255ull; return r; };
  int* cnt      = (int*)alloc(NBUCK * 4);
  unsigned* rec = (unsigned*)alloc((size_t)NBUCK * CAP * 4);
  int* bbase    = (int*)alloc((NBUCK + 1) * 4);
  int* row_ptr  = (int*)alloc((N_NODES + 1) * 4);
  int* colb     = (int*)alloc(((size_t)N_EDGES + 256) * 4);
  unsigned short* xq  = (unsigned short*)alloc((size_t)M_PAD * 64 * 2);
  unsigned short* hqb = (unsigned short*)alloc((size_t)M_PAD * 64 * 2);
  unsigned* hbf  = (unsigned*)alloc((size_t)M_PAD * 64 * 4);
  unsigned* tmpb = (unsigned*)alloc((size_t)M_PAD * 64 * 4);
  unsigned short* Wt1 = (unsigned short*)alloc(3 * DIM * DIM * 2);
  unsigned short* Wt2 = (unsigned short*)alloc(3 * DIM * DIM * 2);
  float* pmax   = (float*)alloc((size_t)XMM_NB * 128 * 4);
  float* pmin   = (float*)alloc((size_t)XMM_NB * 128 * 4);
  float* sA1    = (float*)alloc(384 * 4);
  float* sB1    = (float*)alloc(384 * 4);
  float* sA2    = (float*)alloc(384 * 4);
  float* sB2    = (float*)alloc(384 * 4);
  float* qbuf   = (float*)alloc(1024 * 4);
  float* xmx    = qbuf + 128;    // max(v,0)
  float* xminf  = qbuf + 256;    // min(v,0)
  float* hmax0  = qbuf + 384;
  float* hmax1  = qbuf + 512;
  float* zeros  = qbuf + 640;    // 128 zeros (qmin for relu'd h)
  float* pooled8 = (float*)alloc((size_t)NPOOL * 4);

  k_zeroall<<<(NPOOL + 255) / 256, 256, 0, stream>>>(cnt, (int*)qbuf, (int*)pooled8);

  // CSR build via tiled-reservation counting sort (edges constant across layers)
  k_bucket<<<NTILE, 256, 0, stream>>>(ei, cnt, rec);
  k_bscan<<<1, 512, 0, stream>>>(cnt, bbase, row_ptr);
  k_build<<<NBUCK, 256, 0, stream>>>(rec, cnt, bbase, row_ptr, colb);

  k_xmm1<<<XMM_NB, 256, 0, stream>>>(x, pmax, pmin);
  k_xmm2<<<256, 64, 0, stream>>>(pmax, pmin, xmx, xminf);
  k_convx<<<(M_PAD * 32 + 255) / 256, 256, 0, stream>>>(x, xminf, xmx, xq);
  k_convw<<<(3 * DIM * DIM + 255) / 256, 256, 0, stream>>>(W1, W2, Wt1, Wt2);
  k_coef<<<3, 128, 0, stream>>>(b1, gamma, beta, rmean, rvar, b2, sA1, sB1, sA2, sB2);

  // layer 0
  k_aggr<<<M_PAD / 4, 256, 0, stream>>>(xq, row_ptr, colb, xminf, xmx, tmpb);
  k_gemm12<<<NGB, 256, 0, stream>>>((const unsigned short*)tmpb, Wt1, sA1, sB1,
                                    Wt2, sA2, sB2, batch, (unsigned short*)hbf,
                                    pooled8, 0, hmax0, 1);
  k_quant<<<(M_PAD * 16 + 255) / 256, 256, 0, stream>>>(hbf, hmax0, hqb);
  // layer 1
  k_aggr<<<M_PAD / 4, 256, 0, stream>>>(hqb, row_ptr, colb, zeros, hmax0, tmpb);
  k_gemm12<<<NGB, 256, 0, stream>>>((const unsigned short*)tmpb, Wt1 + DIM * DIM,
                                    sA1 + DIM, sB1 + DIM, Wt2 + DIM * DIM,
                                    sA2 + DIM, sB2 + DIM, batch, (unsigned short*)hbf,
                                    pooled8, 1, hmax1, 1);
  k_quant<<<(M_PAD * 16 + 255) / 256, 256, 0, stream>>>(hbf, hmax1, hqb);
  // layer 2 (h never gathered again: no store/max/quant)
  k_aggr<<<M_PAD / 4, 256, 0, stream>>>(hqb, row_ptr, colb, zeros, hmax1, tmpb);
  k_gemm12<<<NGB, 256, 0, stream>>>((const unsigned short*)tmpb, Wt1 + 2 * DIM * DIM,
                                    sA1 + 2 * DIM, sB1 + 2 * DIM, Wt2 + 2 * DIM * DIM,
                                    sA2 + 2 * DIM, sB2 + 2 * DIM, batch, (unsigned short*)hbf,
                                    pooled8, 2, hmax0, 0);

  k_head<<<N_GRAPHS / 8, 384, 0, stream>>>(pooled8, Wfin, bfin, Wout, bout, out);
}

// Round 6
// 556.070 us; speedup vs baseline: 2.0323x; 1.0398x over previous
//
#include <hip/hip_runtime.h>
#include <stdint.h>

#define N_NODES 100000
#define N_EDGES 3200000
#define N_GRAPHS 512
#define DIM 128
#define M_PAD 100096          // N_NODES padded to multiple of 64
#define NGB (M_PAD / 256)     // 391 gemm blocks (256 rows each)
#define NBUCK 391             // buckets of 256 dst nodes: 391*256 = 100096 >= 100000
#define CAP 9216              // per-bucket region capacity; mean ~8184, sigma ~90
#define TILE 4096             // edges per block in k_bucket
#define NTILE 782             // ceil(3.2M / 4096)
#define XMM_NB 392            // stage-1 blocks for x min/max
#define NPOOL (8 * N_GRAPHS * 384)

typedef __bf16 bf16x8 __attribute__((ext_vector_type(8)));
typedef float f32x4 __attribute__((ext_vector_type(4)));

__device__ __forceinline__ unsigned short f2bf(float f) {
  unsigned u = __float_as_uint(f);
  u = u + 0x7FFFu + ((u >> 16) & 1u);      // round-to-nearest-even
  return (unsigned short)(u >> 16);
}
__device__ __forceinline__ float bflo(unsigned v) { return __uint_as_float(v << 16); }
__device__ __forceinline__ float bfhi(unsigned v) { return __uint_as_float(v & 0xFFFF0000u); }
__device__ __forceinline__ float bfs(unsigned short v) { return __uint_as_float(((unsigned)v) << 16); }
__device__ __forceinline__ unsigned packbf(float a, float b) {
  return (unsigned)f2bf(a) | ((unsigned)f2bf(b) << 16);
}

// ---------------- combined zeroing (one launch) ----------------
__global__ void k_zeroall(int* __restrict__ cnt, int* __restrict__ qbuf,
                          int* __restrict__ pooled) {
  int i = blockIdx.x * 256 + threadIdx.x;
  if (i < NBUCK) cnt[i] = 0;
  if (i < 1024) qbuf[i] = 0;
  if (i < NPOOL) pooled[i] = 0;
}

// ---------------- CSR build: tiled-reservation counting sort ----------------
__global__ __launch_bounds__(256) void k_bucket(const int* __restrict__ ei,
                                                int* __restrict__ cnt,
                                                unsigned* __restrict__ rec) {
  __shared__ int hist[NBUCK];
  __shared__ int curs[NBUCK];
  int t = threadIdx.x;
  int base_e = blockIdx.x * TILE;
  int es[16], ed[16];
#pragma unroll
  for (int k = 0; k < 16; ++k) {
    int e = base_e + k * 256 + t;
    if (e < N_EDGES) { es[k] = ei[e]; ed[k] = ei[N_EDGES + e]; }
    else ed[k] = -1;
  }
  for (int i = t; i < NBUCK; i += 256) hist[i] = 0;
  __syncthreads();
#pragma unroll
  for (int k = 0; k < 16; ++k)
    if (ed[k] >= 0) atomicAdd(&hist[ed[k] >> 8], 1);
  __syncthreads();
  for (int i = t; i < NBUCK; i += 256) {
    int h = hist[i];
    int g = h ? atomicAdd(&cnt[i], h) : 0;
    curs[i] = i * CAP + g;
  }
  __syncthreads();
#pragma unroll
  for (int k = 0; k < 16; ++k) {
    if (ed[k] >= 0) {
      int b = ed[k] >> 8;
      int pos = atomicAdd(&curs[b], 1);
      rec[pos] = ((unsigned)es[k] << 8) | (unsigned)(ed[k] & 255);
    }
  }
}

__global__ __launch_bounds__(512) void k_bscan(const int* __restrict__ cnt,
                                               int* __restrict__ bbase,
                                               int* __restrict__ row_ptr) {
  __shared__ int sc[512];
  int t = threadIdx.x;
  int tot = (t < NBUCK) ? min(cnt[t], CAP) : 0;
  sc[t] = tot; __syncthreads();
  for (int off = 1; off < 512; off <<= 1) {
    int x = (t >= off) ? sc[t - off] : 0;
    __syncthreads();
    sc[t] += x;
    __syncthreads();
  }
  if (t < NBUCK) bbase[t] = sc[t] - tot;                 // exclusive
  if (t == NBUCK - 1) {
    bbase[NBUCK] = sc[t];
    row_ptr[N_NODES] = sc[t];                            // == N_EDGES
  }
}

__global__ __launch_bounds__(256) void k_build(const unsigned* __restrict__ rec,
                                               const int* __restrict__ cnt,
                                               const int* __restrict__ bbase,
                                               int* __restrict__ row_ptr,
                                               int* __restrict__ col) {
  __shared__ int hist[256];
  __shared__ int sc[256];
  __shared__ int curs[256];
  int b = blockIdx.x, t = threadIdx.x;
  int n = min(cnt[b], CAP);
  const unsigned* p = rec + (size_t)b * CAP;
  hist[t] = 0; __syncthreads();
  for (int i = t; i < n; i += 256) atomicAdd(&hist[p[i] & 255u], 1);
  __syncthreads();
  int v = hist[t];
  sc[t] = v; __syncthreads();
  for (int off = 1; off < 256; off <<= 1) {
    int x = (t >= off) ? sc[t - off] : 0;
    __syncthreads();
    sc[t] += x;
    __syncthreads();
  }
  int excl = bbase[b] + sc[t] - v;
  int node = (b << 8) + t;
  if (node < N_NODES) row_ptr[node] = excl;
  curs[t] = excl;
  __syncthreads();
  for (int i = t; i < n; i += 256) {
    unsigned w = p[i];
    int pos = atomicAdd(&curs[w & 255u], 1);
    col[pos] = (int)(w >> 8);
  }
}

// ---------------- x per-column range: two-stage reduction ----------------
__global__ __launch_bounds__(256) void k_xmm1(const float* __restrict__ x,
                                              float* __restrict__ pmax,
                                              float* __restrict__ pmin) {
  __shared__ float smx[8][32][4];
  __shared__ float smn[8][32][4];
  int t = threadIdx.x;
  int c4 = t & 31;          // float4 column group
  int ro = t >> 5;          // 0..7
  float mx0 = 0.f, mx1 = 0.f, mx2 = 0.f, mx3 = 0.f;
  float mn0 = 0.f, mn1 = 0.f, mn2 = 0.f, mn3 = 0.f;
  for (int row = blockIdx.x * 8 + ro; row < N_NODES; row += XMM_NB * 8) {
    float4 v = ((const float4*)x)[(size_t)row * 32 + c4];
    mx0 = fmaxf(mx0, v.x); mn0 = fmaxf(mn0, -v.x);
    mx1 = fmaxf(mx1, v.y); mn1 = fmaxf(mn1, -v.y);
    mx2 = fmaxf(mx2, v.z); mn2 = fmaxf(mn2, -v.z);
    mx3 = fmaxf(mx3, v.w); mn3 = fmaxf(mn3, -v.w);
  }
  smx[ro][c4][0] = mx0; smx[ro][c4][1] = mx1; smx[ro][c4][2] = mx2; smx[ro][c4][3] = mx3;
  smn[ro][c4][0] = mn0; smn[ro][c4][1] = mn1; smn[ro][c4][2] = mn2; smn[ro][c4][3] = mn3;
  __syncthreads();
  for (int off = 4; off > 0; off >>= 1) {
    if (ro < off) {
#pragma unroll
      for (int k = 0; k < 4; ++k) {
        smx[ro][c4][k] = fmaxf(smx[ro][c4][k], smx[ro + off][c4][k]);
        smn[ro][c4][k] = fmaxf(smn[ro][c4][k], smn[ro + off][c4][k]);
      }
    }
    __syncthreads();
  }
  if (ro == 0) {
#pragma unroll
    for (int k = 0; k < 4; ++k) {
      pmax[blockIdx.x * 128 + c4 * 4 + k] = smx[0][c4][k];
      pmin[blockIdx.x * 128 + c4 * 4 + k] = smn[0][c4][k];
    }
  }
}

__global__ __launch_bounds__(64) void k_xmm2(const float* __restrict__ pmax,
                                             const float* __restrict__ pmin,
                                             float* __restrict__ xmx,
                                             float* __restrict__ xminf) {
  int c = blockIdx.x & 127;
  int isMin = blockIdx.x >> 7;
  const float* src = isMin ? pmin : pmax;
  int l = threadIdx.x;
  float m = 0.f;
  for (int p2 = l; p2 < XMM_NB; p2 += 64) m = fmaxf(m, src[p2 * 128 + c]);
#pragma unroll
  for (int off = 32; off > 0; off >>= 1) m = fmaxf(m, __shfl_down(m, off));
  if (l == 0) {
    if (isMin) xminf[c] = -m;
    else xmx[c] = m;
  }
}

// ---------------- conversions / coefficients ----------------
// vectorized x2: one float4 (4 dims) -> one u32 (4 u8) per thread
__global__ void k_convx(const float* __restrict__ x, const float* __restrict__ qmin,
                        const float* __restrict__ qmax, unsigned short* __restrict__ xq) {
  int j = blockIdx.x * 256 + threadIdx.x;
  if (j >= M_PAD * 32) return;
  int k = j & 31;            // float4 group within row
  int node = j >> 5;
  unsigned o = 0;
  if (node < N_NODES) {
    float4 f = ((const float4*)x)[j];
    float4 mn = ((const float4*)qmin)[k];
    float4 mx = ((const float4*)qmax)[k];
    float r0 = mx.x - mn.x, r1 = mx.y - mn.y, r2 = mx.z - mn.z, r3 = mx.w - mn.w;
    float is0 = r0 > 1e-20f ? 255.f / r0 : 0.f;
    float is1 = r1 > 1e-20f ? 255.f / r1 : 0.f;
    float is2 = r2 > 1e-20f ? 255.f / r2 : 0.f;
    float is3 = r3 > 1e-20f ? 255.f / r3 : 0.f;
    int q0 = (int)rintf((f.x - mn.x) * is0); q0 = min(max(q0, 0), 255);
    int q1 = (int)rintf((f.y - mn.y) * is1); q1 = min(max(q1, 0), 255);
    int q2 = (int)rintf((f.z - mn.z) * is2); q2 = min(max(q2, 0), 255);
    int q3 = (int)rintf((f.w - mn.w) * is3); q3 = min(max(q3, 0), 255);
    o = (unsigned)q0 | ((unsigned)q1 << 8) | ((unsigned)q2 << 16) | ((unsigned)q3 << 24);
  }
  ((unsigned*)xq)[j] = o;
}

__device__ __forceinline__ unsigned q1dw(unsigned v, float is0, float is1) {
  int q0 = (int)rintf(bflo(v) * is0); q0 = min(max(q0, 0), 255);
  int q1 = (int)rintf(bfhi(v) * is1); q1 = min(max(q1, 0), 255);
  return (unsigned)(q0 | (q1 << 8));
}

// h (bf16x2-packed) -> u8 (min = 0); vectorized x4 (uint4 in, uint2 out).
// Padding rows forced to ZERO so k_aggr can gather row N_NODES for masked tails.
__global__ void k_quant(const unsigned* __restrict__ hbf, const float* __restrict__ qmax,
                        unsigned short* __restrict__ hq) {
  int j = blockIdx.x * 256 + threadIdx.x;
  if (j >= M_PAD * 16) return;
  int node = j >> 4;
  uint2 o = make_uint2(0u, 0u);
  if (node < N_NODES) {
    int k = j & 15;                       // 8-dim group within row
    uint4 v = ((const uint4*)hbf)[j];
    float4 mxa = ((const float4*)qmax)[2 * k];
    float4 mxb = ((const float4*)qmax)[2 * k + 1];
    float ia0 = mxa.x > 1e-20f ? 255.f / mxa.x : 0.f;
    float ia1 = mxa.y > 1e-20f ? 255.f / mxa.y : 0.f;
    float ia2 = mxa.z > 1e-20f ? 255.f / mxa.z : 0.f;
    float ia3 = mxa.w > 1e-20f ? 255.f / mxa.w : 0.f;
    float ib0 = mxb.x > 1e-20f ? 255.f / mxb.x : 0.f;
    float ib1 = mxb.y > 1e-20f ? 255.f / mxb.y : 0.f;
    float ib2 = mxb.z > 1e-20f ? 255.f / mxb.z : 0.f;
    float ib3 = mxb.w > 1e-20f ? 255.f / mxb.w : 0.f;
    o.x = q1dw(v.x, ia0, ia1) | (q1dw(v.y, ia2, ia3) << 16);
    o.y = q1dw(v.z, ib0, ib1) | (q1dw(v.w, ib2, ib3) << 16);
  }
  ((uint2*)hq)[j] = o;
}

// convw (blocks 0..191) + coef (block 192) merged: one dispatch fewer.
// sA2 dropped entirely (always 1.0 -> phase-2 epilogue is an add).
__global__ void k_convw(const float* __restrict__ W1, const float* __restrict__ W2,
                        unsigned short* __restrict__ Wt1, unsigned short* __restrict__ Wt2,
                        const float* __restrict__ b1, const float* __restrict__ gamma,
                        const float* __restrict__ beta, const float* __restrict__ rmean,
                        const float* __restrict__ rvar, const float* __restrict__ b2,
                        float* __restrict__ sA1, float* __restrict__ sB1,
                        float* __restrict__ sB2) {
  if (blockIdx.x == 192) {
    for (int i = threadIdx.x; i < 3 * DIM; i += 256) {
      float sa = gamma[i] * rsqrtf(rvar[i] + 1e-5f);
      sA1[i] = sa;
      sB1[i] = fmaf(sa, b1[i] - rmean[i], beta[i]);  // sa*(b1-rmean)+beta
      sB2[i] = b2[i];
    }
    return;
  }
  int i = blockIdx.x * 256 + threadIdx.x;              // < 3*DIM*DIM exactly
  int l = i >> 14, rem = i & 16383, k = rem >> 7, n = rem & 127;
  int o = (l << 14) + (n << 7) + k;                    // transposed: Wt[l][n][k]
  Wt1[o] = f2bf(W1[i]);
  Wt2[o] = f2bf(W2[i]);
}

// ---------------- aggregation v4 (u8): dwordx4 gathers, 8 edges per VMEM instr ----------------
// v4 is the measured best (57 us).  Law from v4/v5/v6: dur = FETCH_SIZE / ~2.8-3.2 TB/s
// (scattered L2-fill ceiling, insensitive to ILP/occupancy); v4's FETCH (~158 MB) is
// within ~20% of the per-XCD compulsory floor for a random graph, so this stays.
__global__ __launch_bounds__(256) void k_aggr(const unsigned short* __restrict__ hq,
                                              const int* __restrict__ row_ptr,
                                              const int* __restrict__ col,
                                              const float* __restrict__ qmin,
                                              const float* __restrict__ qmax,
                                              unsigned* __restrict__ tmp) {
  const uint4* hq128 = (const uint4*)hq;     // one row = 8 uint4 (128 B)
  const unsigned* hq32 = (const unsigned*)hq;
  int wv = (blockIdx.x << 2) + (threadIdx.x >> 6);
  int lane = threadIdx.x & 63;
  int grp = lane >> 3;            // edge sub-slot 0..7
  int lo8 = lane & 7;             // which 16 B chunk of the row
  int dw = lane & 31;
  if (wv >= M_PAD) return;
  if (wv >= N_NODES) {
    ((uint2*)(tmp + (size_t)wv * 64))[dw] = make_uint2(0u, 0u);
    return;
  }
  // accumulators: chunk dword k -> ae{k} (dims 4k,4k+2 as u16x2), ao{k} (dims 4k+1,4k+3)
  unsigned ae0 = 0, ae1 = 0, ae2 = 0, ae3 = 0;
  unsigned ao0 = 0, ao1 = 0, ao2 = 0, ao3 = 0;
  int s = __builtin_amdgcn_readfirstlane(row_ptr[wv]);
  int e = __builtin_amdgcn_readfirstlane(row_ptr[wv + 1]);
  int pidx = (lo8 << 3) + grp;    // edge-in-chunk this lane preloads (valid when lo8 < 4)
  for (int base = s; base < e; base += 32) {
    int n = e - base; if (n > 32) n = 32;
    int cv = (pidx < n) ? col[base + pidx] : 0;
    // iteration j: lane gets col of edge 8j+grp  (src lane = (lane&0x38)|j)
    int s0 = __builtin_amdgcn_ds_swizzle(cv, 0x18);   // and=0x18, or=0
    int s1 = __builtin_amdgcn_ds_swizzle(cv, 0x38);   // or=1
    int s2 = __builtin_amdgcn_ds_swizzle(cv, 0x58);   // or=2
    int s3 = __builtin_amdgcn_ds_swizzle(cv, 0x78);   // or=3
    s0 = (grp      < n) ? s0 : N_NODES;
    s1 = (grp +  8 < n) ? s1 : N_NODES;
    s2 = (grp + 16 < n) ? s2 : N_NODES;
    s3 = (grp + 24 < n) ? s3 : N_NODES;
    uint4 v0 = hq128[s0 * 8 + lo8];
    uint4 v1 = hq128[s1 * 8 + lo8];
    uint4 v2 = hq128[s2 * 8 + lo8];
    uint4 v3 = hq128[s3 * 8 + lo8];
    ae0 += v0.x & 0x00FF00FFu; ao0 += (v0.x >> 8) & 0x00FF00FFu;
    ae1 += v0.y & 0x00FF00FFu; ao1 += (v0.y >> 8) & 0x00FF00FFu;
    ae2 += v0.z & 0x00FF00FFu; ao2 += (v0.z >> 8) & 0x00FF00FFu;
    ae3 += v0.w & 0x00FF00FFu; ao3 += (v0.w >> 8) & 0x00FF00FFu;
    ae0 += v1.x & 0x00FF00FFu; ao0 += (v1.x >> 8) & 0x00FF00FFu;
    ae1 += v1.y & 0x00FF00FFu; ao1 += (v1.y >> 8) & 0x00FF00FFu;
    ae2 += v1.z & 0x00FF00FFu; ao2 += (v1.z >> 8) & 0x00FF00FFu;
    ae3 += v1.w & 0x00FF00FFu; ao3 += (v1.w >> 8) & 0x00FF00FFu;
    ae0 += v2.x & 0x00FF00FFu; ao0 += (v2.x >> 8) & 0x00FF00FFu;
    ae1 += v2.y & 0x00FF00FFu; ao1 += (v2.y >> 8) & 0x00FF00FFu;
    ae2 += v2.z & 0x00FF00FFu; ao2 += (v2.z >> 8) & 0x00FF00FFu;
    ae3 += v2.w & 0x00FF00FFu; ao3 += (v2.w >> 8) & 0x00FF00FFu;
    ae0 += v3.x & 0x00FF00FFu; ao0 += (v3.x >> 8) & 0x00FF00FFu;
    ae1 += v3.y & 0x00FF00FFu; ao1 += (v3.y >> 8) & 0x00FF00FFu;
    ae2 += v3.z & 0x00FF00FFu; ao2 += (v3.z >> 8) & 0x00FF00FFu;
    ae3 += v3.w & 0x00FF00FFu; ao3 += (v3.w >> 8) & 0x00FF00FFu;
  }
  // reduce across the 8 edge-slots (lanes differing in bits 3..5)
  ae0 += __shfl_xor(ae0, 8); ae0 += __shfl_xor(ae0, 16); ae0 += __shfl_xor(ae0, 32);
  ae1 += __shfl_xor(ae1, 8); ae1 += __shfl_xor(ae1, 16); ae1 += __shfl_xor(ae1, 32);
  ae2 += __shfl_xor(ae2, 8); ae2 += __shfl_xor(ae2, 16); ae2 += __shfl_xor(ae2, 32);
  ae3 += __shfl_xor(ae3, 8); ae3 += __shfl_xor(ae3, 16); ae3 += __shfl_xor(ae3, 32);
  ao0 += __shfl_xor(ao0, 8); ao0 += __shfl_xor(ao0, 16); ao0 += __shfl_xor(ao0, 32);
  ao1 += __shfl_xor(ao1, 8); ao1 += __shfl_xor(ao1, 16); ao1 += __shfl_xor(ao1, 32);
  ao2 += __shfl_xor(ao2, 8); ao2 += __shfl_xor(ao2, 16); ao2 += __shfl_xor(ao2, 32);
  ao3 += __shfl_xor(ao3, 8); ao3 += __shfl_xor(ao3, 16); ao3 += __shfl_xor(ao3, 32);
  // redistribute to the 32-lane epilogue layout: lane dw wants dword k=dw&3 of chunk dw>>2
  {
    int ba = ((dw >> 2) & 7) << 2;  // byte addr of source lane (holds chunk dw>>2)
    unsigned f0 = (unsigned)__builtin_amdgcn_ds_bpermute(ba, (int)ae0);
    unsigned f1 = (unsigned)__builtin_amdgcn_ds_bpermute(ba, (int)ae1);
    unsigned f2 = (unsigned)__builtin_amdgcn_ds_bpermute(ba, (int)ae2);
    unsigned f3 = (unsigned)__builtin_amdgcn_ds_bpermute(ba, (int)ae3);
    unsigned g0 = (unsigned)__builtin_amdgcn_ds_bpermute(ba, (int)ao0);
    unsigned g1 = (unsigned)__builtin_amdgcn_ds_bpermute(ba, (int)ao1);
    unsigned g2 = (unsigned)__builtin_amdgcn_ds_bpermute(ba, (int)ao2);
    unsigned g3 = (unsigned)__builtin_amdgcn_ds_bpermute(ba, (int)ao3);
    unsigned el = (dw & 1) ? f1 : f0;
    unsigned eh = (dw & 1) ? f3 : f2;
    unsigned ae = (dw & 2) ? eh : el;
    unsigned ol = (dw & 1) ? g1 : g0;
    unsigned oh = (dw & 1) ? g3 : g2;
    unsigned ao = (dw & 2) ? oh : ol;
    if (lane < 32) {
      unsigned v = hq32[wv * 32 + dw];     // self term (eps=0: x + sum_neighbors)
      ae += v & 0x00FF00FFu;
      ao += (v >> 8) & 0x00FF00FFu;
      float cntf = (float)(e - s + 1);
      float4 qn = ((const float4*)qmin)[dw];
      float4 qx = ((const float4*)qmax)[dw];
      const float k255 = 1.0f / 255.0f;
      float A0 = fmaf(qn.x, cntf, (qx.x - qn.x) * k255 * (float)(ae & 0xFFFFu));
      float A1 = fmaf(qn.y, cntf, (qx.y - qn.y) * k255 * (float)(ao & 0xFFFFu));
      float A2 = fmaf(qn.z, cntf, (qx.z - qn.z) * k255 * (float)(ae >> 16));
      float A3 = fmaf(qn.w, cntf, (qx.w - qn.w) * k255 * (float)(ao >> 16));
      ((uint2*)(tmp + (size_t)wv * 64))[dw] = make_uint2(packbf(A0, A1), packbf(A2, A3));
    }
  }
}

// ---------------- fused layer: GEMM1 -> GEMM2 -> pooling (B in regs, z/h in LDS) ----------------
// phase-1: software-pipelined A loads (tile t+1 issued before tile-t MFMAs).
// pooling: 4 row-groups x 64 iters, u32 reads (2 cols/thread) -> serial depth halved.
__global__ __launch_bounds__(256, 2) void k_gemm12(const unsigned short* __restrict__ A,
                                                   const unsigned short* __restrict__ Wt1,
                                                   const float* __restrict__ sA1,
                                                   const float* __restrict__ sB1,
                                                   const unsigned short* __restrict__ Wt2,
                                                   const float* __restrict__ sB2,
                                                   const int* __restrict__ batch,
                                                   unsigned short* __restrict__ out,
                                                   float* __restrict__ pooled8, int layer,
                                                   float* __restrict__ hmax, int do_max) {
  __shared__ unsigned short zt[4][64][136];   // z then h, wave-private rows
  __shared__ float colred[128];
  __shared__ int sgid[256];
  int w = threadIdx.x >> 6, lane = threadIdx.x & 63;
  int q = lane >> 4, n16 = lane & 15;
  int rbase = (blockIdx.x << 8) + (w << 6);
  if (do_max && threadIdx.x < 128) colred[threadIdx.x] = 0.f;
  {
    int rr = (blockIdx.x << 8) + threadIdx.x;
    sgid[threadIdx.x] = (rr < N_NODES) ? batch[rr] : -1;
  }

  // ---- phase 1: B1 in registers, z -> LDS ----
  {
    bf16x8 Bf[4][8];
#pragma unroll
    for (int ks = 0; ks < 4; ++ks)
#pragma unroll
      for (int c = 0; c < 8; ++c)
        Bf[ks][c] = *(const bf16x8*)(Wt1 + (size_t)((c << 4) + n16) * DIM + ks * 32 + q * 8);
    bf16x8 an0, an1, an2, an3;
    {
      const unsigned short* ap = A + (size_t)(rbase + n16) * DIM + q * 8;
      an0 = *(const bf16x8*)(ap);
      an1 = *(const bf16x8*)(ap + 32);
      an2 = *(const bf16x8*)(ap + 64);
      an3 = *(const bf16x8*)(ap + 96);
    }
#pragma unroll
    for (int t = 0; t < 4; ++t) {
      bf16x8 a0 = an0, a1 = an1, a2 = an2, a3 = an3;
      if (t < 3) {   // prefetch next tile's A while computing this one
        const unsigned short* ap = A + (size_t)(rbase + ((t + 1) << 4) + n16) * DIM + q * 8;
        an0 = *(const bf16x8*)(ap);
        an1 = *(const bf16x8*)(ap + 32);
        an2 = *(const bf16x8*)(ap + 64);
        an3 = *(const bf16x8*)(ap + 96);
      }
      f32x4 acc[8] = {};
#pragma unroll
      for (int c = 0; c < 8; ++c) acc[c] = __builtin_amdgcn_mfma_f32_16x16x32_bf16(a0, Bf[0][c], acc[c], 0, 0, 0);
#pragma unroll
      for (int c = 0; c < 8; ++c) acc[c] = __builtin_amdgcn_mfma_f32_16x16x32_bf16(a1, Bf[1][c], acc[c], 0, 0, 0);
#pragma unroll
      for (int c = 0; c < 8; ++c) acc[c] = __builtin_amdgcn_mfma_f32_16x16x32_bf16(a2, Bf[2][c], acc[c], 0, 0, 0);
#pragma unroll
      for (int c = 0; c < 8; ++c) acc[c] = __builtin_amdgcn_mfma_f32_16x16x32_bf16(a3, Bf[3][c], acc[c], 0, 0, 0);
#pragma unroll
      for (int c = 0; c < 8; ++c) {
        int colc = (c << 4) + n16;
        float s = sA1[colc], tt = sB1[colc];
#pragma unroll
        for (int r = 0; r < 4; ++r) {
          float v = fmaxf(fmaf(s, acc[c][r], tt), 0.0f);
          zt[w][(t << 4) + (q << 2) + r][colc] = f2bf(v);
        }
      }
    }
  }

  // ---- phase 2: B2 in registers, A from LDS; h -> LDS ----
  float mcol[8];
#pragma unroll
  for (int c = 0; c < 8; ++c) mcol[c] = 0.f;
  {
    bf16x8 Bf[4][8];
#pragma unroll
    for (int ks = 0; ks < 4; ++ks)
#pragma unroll
      for (int c = 0; c < 8; ++c)
        Bf[ks][c] = *(const bf16x8*)(Wt2 + (size_t)((c << 4) + n16) * DIM + ks * 32 + q * 8);
#pragma unroll
    for (int t = 0; t < 4; ++t) {
      f32x4 acc[8] = {};
#pragma unroll
      for (int ks = 0; ks < 4; ++ks) {
        bf16x8 a = *(const bf16x8*)(&zt[w][(t << 4) + n16][ks * 32 + q * 8]);
#pragma unroll
        for (int c = 0; c < 8; ++c)
          acc[c] = __builtin_amdgcn_mfma_f32_16x16x32_bf16(a, Bf[ks][c], acc[c], 0, 0, 0);
      }
      // only LDS ordering needed: zt reads of tile t must finish before overwrite
      asm volatile("s_waitcnt lgkmcnt(0)" ::: "memory");
#pragma unroll
      for (int c = 0; c < 8; ++c) {
        int colc = (c << 4) + n16;
        float tt = sB2[colc];
#pragma unroll
        for (int r = 0; r < 4; ++r) {
          float v = fmaxf(acc[c][r] + tt, 0.0f);    // sA2 == 1.0 always
          mcol[c] = fmaxf(mcol[c], v);
          zt[w][(t << 4) + (q << 2) + r][colc] = f2bf(v);
        }
      }
    }
  }
  __syncthreads();   // h tiles + sgid visible to all

  // ---- bulk coalesced h store (only when a later layer re-reads h) ----
  if (do_max) {
    const unsigned short* ztf = &zt[0][0][0];
    int chunk = threadIdx.x & 15;          // 16 B chunk within a 256 B row
    int rsub  = threadIdx.x >> 4;          // 0..15
    unsigned short* ob = out + ((size_t)blockIdx.x << 8) * DIM;
#pragma unroll
    for (int i = 0; i < 16; ++i) {
      int r = (i << 4) + rsub;             // 0..255
      uint4 v = *(const uint4*)(ztf + r * 136 + chunk * 8);
      *(uint4*)(ob + r * DIM + chunk * 8) = v;
    }
  }

  // ---- pooling: segment-sum sorted rows, one atomic pair per (segment, col-pair) ----
  {
    const unsigned* ztu = (const unsigned*)&zt[0][0][0];   // 68 u32 per row
    int cp2 = threadIdx.x & 63;            // col pair: cols 2*cp2, 2*cp2+1
    int grp = threadIdx.x >> 6;            // 0..3, rows grp*64 .. grp*64+63
    int cpy = blockIdx.x & 7;
    float pacc0 = 0.f, pacc1 = 0.f;
    int gcur = sgid[grp << 6];
    for (int r = 0; r < 64; ++r) {
      int row = (grp << 6) + r;
      int g = sgid[row];
      if (g != gcur) {
        if (gcur >= 0) {
          float* bp = &pooled8[((size_t)cpy * N_GRAPHS + gcur) * 384 + layer * DIM + 2 * cp2];
          atomicAdd(bp, pacc0);
          atomicAdd(bp + 1, pacc1);
        }
        pacc0 = 0.f; pacc1 = 0.f; gcur = g;
      }
      if (g >= 0) {
        unsigned v = ztu[row * 68 + cp2];
        pacc0 += bflo(v);
        pacc1 += bfhi(v);
      }
    }
    if (gcur >= 0) {
      float* bp = &pooled8[((size_t)cpy * N_GRAPHS + gcur) * 384 + layer * DIM + 2 * cp2];
      atomicAdd(bp, pacc0);
      atomicAdd(bp + 1, pacc1);
    }
  }

  if (do_max) {
#pragma unroll
    for (int c = 0; c < 8; ++c)
      atomicMax((int*)&colred[(c << 4) + n16], __float_as_int(mcol[c]));
    __syncthreads();
    if (threadIdx.x < 128)
      atomicMax((int*)&hmax[threadIdx.x], __float_as_int(colred[threadIdx.x]));
  }
}

// ---------------- head: 8 graphs per block, sums the 8 pooled copies ----------------
__global__ __launch_bounds__(384) void k_head(const float* __restrict__ pooled8,
                                              const float* __restrict__ Wfin,
                                              const float* __restrict__ bfin,
                                              const float* __restrict__ Wout,
                                              const float* __restrict__ bout,
                                              float* __restrict__ out) {
  __shared__ float p[8][384];
  __shared__ float hf[8][392];
  __shared__ float lg[8][10];
  __shared__ float lse[8];
  int t = threadIdx.x, g0 = blockIdx.x << 3;
  for (int i = t; i < 8 * 384; i += 384) {
    int gl = i / 384, k = i % 384;
    float s = 0.f;
#pragma unroll
    for (int cp = 0; cp < 8; ++cp)
      s += pooled8[((size_t)cp * N_GRAPHS + g0 + gl) * 384 + k];
    p[gl][k] = s;
  }
  __syncthreads();
  float bb = bfin[t];
  float acc[8];
#pragma unroll
  for (int g = 0; g < 8; ++g) acc[g] = bb;
  for (int k = 0; k < 384; ++k) {
    float wv = Wfin[k * 384 + t];
#pragma unroll
    for (int g = 0; g < 8; ++g) acc[g] = fmaf(p[g][k], wv, acc[g]);
  }
#pragma unroll
  for (int g = 0; g < 8; ++g) hf[g][t] = fmaxf(acc[g], 0.f);
  __syncthreads();
  if (t < 80) {
    int g = t / 10, c = t % 10;
    float a = bout[c];
    for (int k = 0; k < 384; ++k) a = fmaf(hf[g][k], Wout[k * 10 + c], a);
    lg[g][c] = a;
  }
  __syncthreads();
  if (t < 8) {
    float m = lg[t][0];
#pragma unroll
    for (int i = 1; i < 10; ++i) m = fmaxf(m, lg[t][i]);
    float ss = 0.f;
#pragma unroll
    for (int i = 0; i < 10; ++i) ss += __expf(lg[t][i] - m);
    lse[t] = m + __logf(ss);
  }
  __syncthreads();
  if (t < 80) {
    int g = t / 10, c = t % 10;
    out[(size_t)(g0 + g) * 10 + c] = lg[g][c];
    out[(size_t)N_GRAPHS * 10 + (size_t)(g0 + g) * 10 + c] = lg[g][c] - lse[g];
  }
}

extern "C" void kernel_launch(void* const* d_in, const int* in_sizes, int n_in,
                              void* d_out, int out_size, void* d_ws, size_t ws_size,
                              hipStream_t stream) {
  const float* x     = (const float*)d_in[0];
  const int*   ei    = (const int*)d_in[1];    // [2, N_EDGES]: src then dst
  const int*   batch = (const int*)d_in[2];
  const float* W1    = (const float*)d_in[4];
  const float* b1    = (const float*)d_in[5];
  const float* gamma = (const float*)d_in[6];
  const float* beta  = (const float*)d_in[7];
  const float* rmean = (const float*)d_in[8];
  const float* rvar  = (const float*)d_in[9];
  const float* W2    = (const float*)d_in[10];
  const float* b2    = (const float*)d_in[11];
  const float* Wfin  = (const float*)d_in[12];
  const float* bfin  = (const float*)d_in[13];
  const float* Wout  = (const float*)d_in[14];
  const float* bout  = (const float*)d_in[15];
  float* out = (float*)d_out;

  char* p = (char*)d_ws;
  auto alloc = [&](size_t bytes) { char* r = p; p += (bytes + 255) & ~255ull; return r; };
  int* cnt      = (int*)alloc(NBUCK * 4);
  unsigned* rec = (unsigned*)alloc((size_t)NBUCK * CAP * 4);
  int* bbase    = (int*)alloc((NBUCK + 1) * 4);
  int* row_ptr  = (int*)alloc((N_NODES + 1) * 4);
  int* colb     = (int*)alloc(((size_t)N_EDGES + 256) * 4);
  unsigned short* xq  = (unsigned short*)alloc((size_t)M_PAD * 64 * 2);
  unsigned short* hqb = (unsigned short*)alloc((size_t)M_PAD * 64 * 2);
  unsigned* hbf  = (unsigned*)alloc((size_t)M_PAD * 64 * 4);
  unsigned* tmpb = (unsigned*)alloc((size_t)M_PAD * 64 * 4);
  unsigned short* Wt1 = (unsigned short*)alloc(3 * DIM * DIM * 2);
  unsigned short* Wt2 = (unsigned short*)alloc(3 * DIM * DIM * 2);
  float* pmax   = (float*)alloc((size_t)XMM_NB * 128 * 4);
  float* pmin   = (float*)alloc((size_t)XMM_NB * 128 * 4);
  float* sA1    = (float*)alloc(384 * 4);
  float* sB1    = (float*)alloc(384 * 4);
  float* sB2    = (float*)alloc(384 * 4);
  float* qbuf   = (float*)alloc(1024 * 4);
  float* xmx    = qbuf + 128;    // max(v,0)
  float* xminf  = qbuf + 256;    // min(v,0)
  float* hmax0  = qbuf + 384;
  float* hmax1  = qbuf + 512;
  float* zeros  = qbuf + 640;    // 128 zeros (qmin for relu'd h)
  float* pooled8 = (float*)alloc((size_t)NPOOL * 4);

  k_zeroall<<<(NPOOL + 255) / 256, 256, 0, stream>>>(cnt, (int*)qbuf, (int*)pooled8);

  // CSR build via tiled-reservation counting sort (edges constant across layers)
  k_bucket<<<NTILE, 256, 0, stream>>>(ei, cnt, rec);
  k_bscan<<<1, 512, 0, stream>>>(cnt, bbase, row_ptr);
  k_build<<<NBUCK, 256, 0, stream>>>(rec, cnt, bbase, row_ptr, colb);

  k_xmm1<<<XMM_NB, 256, 0, stream>>>(x, pmax, pmin);
  k_xmm2<<<256, 64, 0, stream>>>(pmax, pmin, xmx, xminf);
  k_convx<<<(M_PAD * 32 + 255) / 256, 256, 0, stream>>>(x, xminf, xmx, xq);
  k_convw<<<193, 256, 0, stream>>>(W1, W2, Wt1, Wt2, b1, gamma, beta, rmean, rvar, b2,
                                   sA1, sB1, sB2);

  // layer 0
  k_aggr<<<M_PAD / 4, 256, 0, stream>>>(xq, row_ptr, colb, xminf, xmx, tmpb);
  k_gemm12<<<NGB, 256, 0, stream>>>((const unsigned short*)tmpb, Wt1, sA1, sB1,
                                    Wt2, sB2, batch, (unsigned short*)hbf,
                                    pooled8, 0, hmax0, 1);
  k_quant<<<(M_PAD * 16 + 255) / 256, 256, 0, stream>>>(hbf, hmax0, hqb);
  // layer 1
  k_aggr<<<M_PAD / 4, 256, 0, stream>>>(hqb, row_ptr, colb, zeros, hmax0, tmpb);
  k_gemm12<<<NGB, 256, 0, stream>>>((const unsigned short*)tmpb, Wt1 + DIM * DIM,
                                    sA1 + DIM, sB1 + DIM, Wt2 + DIM * DIM,
                                    sB2 + DIM, batch, (unsigned short*)hbf,
                                    pooled8, 1, hmax1, 1);
  k_quant<<<(M_PAD * 16 + 255) / 256, 256, 0, stream>>>(hbf, hmax1, hqb);
  // layer 2 (h never gathered again: no store/max/quant)
  k_aggr<<<M_PAD / 4, 256, 0, stream>>>(hqb, row_ptr, colb, zeros, hmax1, tmpb);
  k_gemm12<<<NGB, 256, 0, stream>>>((const unsigned short*)tmpb, Wt1 + 2 * DIM * DIM,
                                    sA1 + 2 * DIM, sB1 + 2 * DIM, Wt2 + 2 * DIM * DIM,
                                    sB2 + 2 * DIM, batch, (unsigned short*)hbf,
                                    pooled8, 2, hmax0, 0);

  k_head<<<N_GRAPHS / 8, 384, 0, stream>>>(pooled8, Wfin, bfin, Wout, bout, out);
}